// Round 7
// baseline (1441.481 us; speedup 1.0000x reference)
//
#include <hip/hip_runtime.h>
#include <cstdint>
#include <cstddef>

typedef __bf16 bf16x8 __attribute__((ext_vector_type(8)));
typedef __bf16 bf16x4 __attribute__((ext_vector_type(4)));
typedef float  f32x4  __attribute__((ext_vector_type(4)));

#define TOKENS  4096
#define SEQLEN  2048
#define HID     2048
#define QKV_W   6144
#define UP_W    8192
#define INTER_  4096

__device__ __forceinline__ void async16(const void* g, void* l) {
  __builtin_amdgcn_global_load_lds(
      (__attribute__((address_space(1))) void*)(g),
      (__attribute__((address_space(3))) void*)(l), 16, 0, 0);
}

// ---------------- fp32 -> bf16 weight convert ----------------
__global__ __launch_bounds__(256) void cvt_kernel(const float* __restrict__ src,
                                                  __bf16* __restrict__ dst, int n4) {
  int i = blockIdx.x * 256 + threadIdx.x;
  if (i >= n4) return;
  float4 f = ((const float4*)src)[i];
  bf16x4 o;
  o[0] = (__bf16)f.x; o[1] = (__bf16)f.y; o[2] = (__bf16)f.z; o[3] = (__bf16)f.w;
  ((bf16x4*)dst)[i] = o;
}

// ---------------- rmsnorm: fp32 in -> bf16 out ----------------
__global__ __launch_bounds__(256) void rmsnorm_kernel(const float* __restrict__ x,
                                                      const float* __restrict__ wgt,
                                                      __bf16* __restrict__ out) {
  const int tok = blockIdx.x;
  const int t = threadIdx.x;
  const float4* xr = (const float4*)(x + (long)tok * HID);
  float4 a = xr[t], b = xr[t + 256];
  float ss = a.x*a.x + a.y*a.y + a.z*a.z + a.w*a.w
           + b.x*b.x + b.y*b.y + b.z*b.z + b.w*b.w;
  #pragma unroll
  for (int off = 32; off; off >>= 1) ss += __shfl_xor(ss, off);
  __shared__ float red[4];
  if ((t & 63) == 0) red[t >> 6] = ss;
  __syncthreads();
  float tot = red[0] + red[1] + red[2] + red[3];
  float r = rsqrtf(tot * (1.0f / HID) + 1e-5f);
  const float4* wr = (const float4*)wgt;
  float4 wa = wr[t], wb = wr[t + 256];
  bf16x4 o0, o1;
  o0[0] = (__bf16)(a.x * r * wa.x); o0[1] = (__bf16)(a.y * r * wa.y);
  o0[2] = (__bf16)(a.z * r * wa.z); o0[3] = (__bf16)(a.w * r * wa.w);
  o1[0] = (__bf16)(b.x * r * wb.x); o1[1] = (__bf16)(b.y * r * wb.y);
  o1[2] = (__bf16)(b.z * r * wb.z); o1[3] = (__bf16)(b.w * r * wb.w);
  bf16x4* orow = (bf16x4*)(out + (long)tok * HID);
  orow[t] = o0; orow[t + 256] = o1;
}

// ---------------- OLD BK=64 bf16 GEMM (round-0, verified) -- O, Down, V-proj ----
template<bool OUT_BF16, bool ADD_RES, bool ROPE, bool SILU>
__global__ __launch_bounds__(256) void gemm_bt(const __bf16* __restrict__ A, int lda,
                                               const __bf16* __restrict__ B, int ldb,
                                               void* Cv, int ldc,
                                               const float* __restrict__ Res, int K) {
  __shared__ __align__(16) __bf16 As[128 * 64];
  __shared__ __align__(16) __bf16 Bs[128 * 64];
  const int t = threadIdx.x;
  const int lane = t & 63;
  const int w = t >> 6;
  const int wm = (w >> 1) * 64, wn = (w & 1) * 64;
  const int m0 = blockIdx.y * 128;
  const int n0 = SILU ? blockIdx.x * 64 : blockIdx.x * 128;
  const int sr = t >> 3;
  const int sc = (((t & 7) ^ (sr & 7)) * 8);
  const __bf16* Ag = A + (long)(m0 + sr) * lda + sc;
  const __bf16* Bg = B + (long)(n0 + sr) * ldb + sc;
  char* lA = (char*)As + t * 16;
  char* lB = (char*)Bs + t * 16;
  const int lr = lane & 15;
  const int lq = lane >> 4;
  f32x4 acc[4][4] = {};
  for (int k0 = 0; k0 < K; k0 += 64) {
    __syncthreads();
    #pragma unroll
    for (int c = 0; c < 4; c++)
      async16(Ag + (long)(c * 32) * lda + k0, lA + c * 4096);
    #pragma unroll
    for (int c = 0; c < 4; c++) {
      const long rowoff = SILU ? (long)((c & 1) * INTER_ + (c >> 1) * 32) * ldb
                               : (long)(c * 32) * ldb;
      async16(Bg + rowoff + k0, lB + c * 4096);
    }
    __syncthreads();
    #pragma unroll
    for (int ks = 0; ks < 2; ks++) {
      const int pos = (((ks * 4 + lq) ^ (lr & 7)) * 8);
      bf16x8 af[4], bfr[4];
      #pragma unroll
      for (int i = 0; i < 4; i++)
        af[i]  = *(const bf16x8*)(As + (wm + i * 16 + lr) * 64 + pos);
      #pragma unroll
      for (int j = 0; j < 4; j++)
        bfr[j] = *(const bf16x8*)(Bs + (wn + j * 16 + lr) * 64 + pos);
      #pragma unroll
      for (int i = 0; i < 4; i++)
        #pragma unroll
        for (int j = 0; j < 4; j++)
          acc[i][j] = __builtin_amdgcn_mfma_f32_16x16x32_bf16(af[i], bfr[j], acc[i][j], 0, 0, 0);
    }
  }
  const int lq4 = lq * 4;
  #pragma unroll
  for (int i = 0; i < 4; i++) {
    #pragma unroll
    for (int r = 0; r < 4; r++) {
      const long row = m0 + wm + i * 16 + lq4 + r;
      #pragma unroll
      for (int j = 0; j < 4; j++) {
        const long col = n0 + wn + j * 16 + lr;
        float v = acc[i][j][r];
        if (ADD_RES) v += Res[row * (long)ldc + col];
        if (OUT_BF16) ((__bf16*)Cv)[row * (long)ldc + col] = (__bf16)v;
        else          ((float*)Cv)[row * (long)ldc + col] = v;
      }
    }
  }
}

// ---------------- 8-phase 256x256 pipelined GEMM v3 (round-3, verified 983 TF) --------
// Used for QK (rope). BK=64, 128 KiB LDS, 1 block/CU.
template<bool ROPE, bool SILU>
__global__ __launch_bounds__(512, 2) void gemm8p(const __bf16* __restrict__ A, int lda,
                                                 const __bf16* __restrict__ B, int ldb,
                                                 void* Cv, int ldc, int K) {
  __shared__ __align__(16) __bf16 As[2 * 16384];   // 2 x 32 KiB
  __shared__ __align__(16) __bf16 Bs[2 * 16384];   // 2 x 32 KiB
  const int tid  = threadIdx.x;
  const int lane = tid & 63;
  const int w    = tid >> 6;
  const int wm2  = w >> 2;        // 0..1
  const int wn4  = w & 3;         // 0..3
  const int lr   = lane & 15;
  const int lq   = lane >> 4;
  const int m0   = blockIdx.y * 256;
  const int n0   = ROPE ? blockIdx.x * 256 : 0;
  const int n0c  = SILU ? blockIdx.x * 128 : 0;

  const long r0 = tid >> 3;
  const int  e  = (((tid & 7) ^ ((int)r0 & 7)) * 8);
  const __bf16* Ap0 = A + (long)(m0 + r0) * lda + e;
  long br0, br1, bhs;
  if (ROPE) {
    br0 = n0 + 64 * (((int)r0 >> 5) & 3) + ((int)r0 & 31);
    br1 = n0 + 64 * ((((int)r0 + 64) >> 5) & 3) + ((int)r0 & 31);
    bhs = 32 * (long)ldb;
  } else {
    br0 = n0c + r0;
    br1 = n0c + r0 + 64;
    bhs = (long)INTER_ * ldb;
  }
  const __bf16* Bp0 = B + br0 * ldb + e;
  const __bf16* Bp1 = B + br1 * ldb + e;
  char* sA = (char*)As;
  char* sB = (char*)Bs;
  const int tid16 = tid * 16;

#define STAGE_A(h_, nb_, kk_) do {                                                     \
    async16(Ap0 + (long)((h_) * 128) * lda + (kk_),      sA + (nb_)*32768 + (h_)*16384 + tid16);        \
    async16(Ap0 + (long)((h_) * 128 + 64) * lda + (kk_), sA + (nb_)*32768 + (h_)*16384 + 8192 + tid16); \
  } while (0)
#define STAGE_B(h_, nb_, kk_) do {                                                     \
    async16(Bp0 + (h_) * bhs + (kk_), sB + (nb_)*32768 + (h_)*16384 + tid16);          \
    async16(Bp1 + (h_) * bhs + (kk_), sB + (nb_)*32768 + (h_)*16384 + 8192 + tid16);   \
  } while (0)

  const int ch0 = ((lq ^ (lr & 7)) * 16);
  const int ch1 = (((4 + lq) ^ (lr & 7)) * 16);
  const int abase = (wm2 * 64 + lr) * 128;
  const int bbase = (wn4 * 32 + lr) * 128;

  f32x4 acc[8][4] = {};
  bf16x8 af[4][2], bfr[4][2];
  const int NT = K >> 6;

#define LOAD_A(mh_) do {                                                               \
    _Pragma("unroll")                                                                  \
    for (int i = 0; i < 4; i++) {                                                      \
      af[i][0] = *(const bf16x8*)(Ab + abase + (mh_)*16384 + i*2048 + ch0);            \
      af[i][1] = *(const bf16x8*)(Ab + abase + (mh_)*16384 + i*2048 + ch1);            \
    } } while (0)
#define LOAD_B(nh_) do {                                                               \
    _Pragma("unroll")                                                                  \
    for (int j = 0; j < 2; j++) {                                                      \
      bfr[(nh_)*2 + j][0] = *(const bf16x8*)(Bb + bbase + (nh_)*16384 + j*2048 + ch0); \
      bfr[(nh_)*2 + j][1] = *(const bf16x8*)(Bb + bbase + (nh_)*16384 + j*2048 + ch1); \
    } } while (0)
#define MFMA_Q(mh_, nh_) do {                                                          \
    __builtin_amdgcn_s_setprio(1);                                                     \
    _Pragma("unroll")                                                                  \
    for (int ks = 0; ks < 2; ks++)                                                     \
      _Pragma("unroll")                                                                \
      for (int i = 0; i < 4; i++)                                                      \
        _Pragma("unroll")                                                              \
        for (int j = 0; j < 2; j++)                                                    \
          acc[(mh_)*4 + i][(nh_)*2 + j] = __builtin_amdgcn_mfma_f32_16x16x32_bf16(     \
              af[i][ks], bfr[(nh_)*2 + j][ks], acc[(mh_)*4 + i][(nh_)*2 + j], 0, 0, 0);\
    __builtin_amdgcn_s_setprio(0);                                                     \
  } while (0)
#define SBAR() do { __builtin_amdgcn_sched_barrier(0);                                 \
    __builtin_amdgcn_s_barrier(); __builtin_amdgcn_sched_barrier(0); } while (0)
#define LGKM0() do { asm volatile("s_waitcnt lgkmcnt(0)" ::: "memory");                \
    __builtin_amdgcn_sched_barrier(0); } while (0)

  STAGE_A(0, 0, 0); STAGE_B(0, 0, 0); STAGE_B(1, 0, 0); STAGE_A(1, 0, 0);
  asm volatile("s_waitcnt vmcnt(4)" ::: "memory");
  SBAR();

  for (int T = 0; T < NT; ++T) {
    const int cb = T & 1, nb = cb ^ 1;
    const int kk = (T + 1) << 6;
    const bool st = (T + 1 < NT);
    const char* Ab = (const char*)As + cb * 32768;
    const char* Bb = (const char*)Bs + cb * 32768;
    LOAD_A(0); LOAD_B(0);
    if (st) { STAGE_A(0, nb, kk); STAGE_B(0, nb, kk); }
    SBAR(); LGKM0();
    MFMA_Q(0, 0);
    if (st) asm volatile("s_waitcnt vmcnt(6)" ::: "memory");
    else    asm volatile("s_waitcnt vmcnt(2)" ::: "memory");
    SBAR();
    LOAD_B(1);
    if (st) STAGE_B(1, nb, kk);
    SBAR(); LGKM0();
    MFMA_Q(0, 1);
    if (st) asm volatile("s_waitcnt vmcnt(6)" ::: "memory");
    else    asm volatile("s_waitcnt vmcnt(0)" ::: "memory");
    SBAR();
    LOAD_A(1);
    if (st) STAGE_A(1, nb, kk);
    SBAR(); LGKM0();
    MFMA_Q(1, 0);
    SBAR();
    MFMA_Q(1, 1);
    if (st) asm volatile("s_waitcnt vmcnt(4)" ::: "memory");
    SBAR();
  }
#undef STAGE_A
#undef STAGE_B
#undef LOAD_A
#undef LOAD_B
#undef MFMA_Q
#undef SBAR
#undef LGKM0

  const int lq4 = lq * 4;
  if (ROPE) {
    if (n0 < 4096) {
      const float invf0 = exp2f((float)(lr)      * -0.41524101186092029f);
      const float invf1 = exp2f((float)(16 + lr) * -0.41524101186092029f);
      #pragma unroll
      for (int mi = 0; mi < 8; mi++) {
        #pragma unroll
        for (int r = 0; r < 4; r++) {
          const long row = m0 + (mi >> 2) * 128 + wm2 * 64 + (mi & 3) * 16 + lq4 + r;
          const float s = (float)(int)(row & (SEQLEN - 1));
          __bf16* crow = (__bf16*)Cv + row * (long)ldc + n0 + wn4 * 64 + lr;
          #pragma unroll
          for (int nj = 0; nj < 2; nj++) {
            float x1 = acc[mi][nj][r], x2 = acc[mi][nj + 2][r];
            float ang = s * (nj ? invf1 : invf0);
            float sn, cs;
            __sincosf(ang, &sn, &cs);
            crow[nj * 16]      = (__bf16)(x1 * cs - x2 * sn);
            crow[nj * 16 + 32] = (__bf16)(x2 * cs + x1 * sn);
          }
        }
      }
    } else {
      #pragma unroll
      for (int mi = 0; mi < 8; mi++) {
        #pragma unroll
        for (int r = 0; r < 4; r++) {
          const long row = m0 + (mi >> 2) * 128 + wm2 * 64 + (mi & 3) * 16 + lq4 + r;
          __bf16* crow = (__bf16*)Cv + row * (long)ldc + n0 + wn4 * 64 + lr;
          #pragma unroll
          for (int njf = 0; njf < 4; njf++)
            crow[(njf >> 1) * 32 + (njf & 1) * 16] = (__bf16)acc[mi][njf][r];
        }
      }
    }
  } else {  // SILU
    #pragma unroll
    for (int mi = 0; mi < 8; mi++) {
      #pragma unroll
      for (int r = 0; r < 4; r++) {
        const long row = m0 + (mi >> 2) * 128 + wm2 * 64 + (mi & 3) * 16 + lq4 + r;
        #pragma unroll
        for (int nj = 0; nj < 2; nj++) {
          const long col = n0c + wn4 * 32 + nj * 16 + lr;
          float g = acc[mi][nj][r];
          float v = acc[mi][nj + 2][r];
          float sg = g / (1.0f + __expf(-g));
          ((__bf16*)Cv)[row * (long)ldc + col] = (__bf16)(sg * v);
        }
      }
    }
  }
}

// ---------------- NEW: BK=32 8-phase GEMM, 64 KiB LDS -> 2 blocks/CU (Up only) -------
// Same 512-thr / 8-wave / per-wave 128x64 / 4-phase skeleton, pins, setprio, and
// derived-vmcnt discipline as gemm8p v3; parameters halved: 1 k-slice per fragment,
// 1 async16 per half-tile (4 stages/tile), vmcnt 3/3/-/2 steady (1/0 tail).
// Swizzle for 64B rows: read position p=(lq+((lr>>1)&3))&3 (2-way bank spread, free);
// stage source chunk g=((tid&3)-((tid>>3)&3))&3 (bijective inverse, LDS dest linear).
// SILU fixed: B-half0 = gate rows n0c+0..127, B-half1 = value rows INTER_+n0c+0..127.
__global__ __launch_bounds__(512, 4) void gemm_up32(const __bf16* __restrict__ A, int lda,
                                                    const __bf16* __restrict__ B, int ldb,
                                                    void* Cv, int ldc, int K) {
  __shared__ __align__(16) __bf16 As[2 * 8192];   // 2 x 16 KiB
  __shared__ __align__(16) __bf16 Bs[2 * 8192];   // 2 x 16 KiB
  const int tid  = threadIdx.x;
  const int lane = tid & 63;
  const int w    = tid >> 6;
  const int wm2  = w >> 2;
  const int wn4  = w & 3;
  const int lr   = lane & 15;
  const int lq   = lane >> 4;
  const int m0   = blockIdx.y * 256;
  const int n0c  = blockIdx.x * 128;

  const int sr = tid >> 2;                              // 0..127
  const int g8 = ((((tid & 3) - ((tid >> 3) & 3)) & 3) * 8);
  const __bf16* ApS = A + (long)(m0 + sr) * lda + g8;
  const __bf16* BpS = B + (long)(n0c + sr) * ldb + g8;
  char* sA = (char*)As;
  char* sB = (char*)Bs;
  const int tid16 = tid * 16;

#define STAGE_A32(h_, nb_, kk_) \
    async16(ApS + (long)((h_) * 128) * lda + (kk_), sA + (nb_)*16384 + (h_)*8192 + tid16)
#define STAGE_B32(h_, nb_, kk_) \
    async16(BpS + (h_) * ((long)INTER_ * ldb) + (kk_), sB + (nb_)*16384 + (h_)*8192 + tid16)

  const int p16   = ((lq + ((lr >> 1) & 3)) & 3) * 16;
  const int abase = (wm2 * 64 + lr) * 64 + p16;
  const int bbase = (wn4 * 32 + lr) * 64 + p16;

  f32x4 acc[8][4] = {};
  bf16x8 af[4], bfr[4];
  const int NT = K >> 5;

#define LOAD_A32(mh_, buf_) do {                                                       \
    const char* p_ = sA + (buf_)*16384 + (mh_)*8192 + abase;                           \
    _Pragma("unroll")                                                                  \
    for (int i = 0; i < 4; i++) af[i] = *(const bf16x8*)(p_ + i * 1024);               \
  } while (0)
#define LOAD_B32(nh_, buf_) do {                                                       \
    const char* p_ = sB + (buf_)*16384 + (nh_)*8192 + bbase;                           \
    _Pragma("unroll")                                                                  \
    for (int j = 0; j < 2; j++) bfr[(nh_)*2 + j] = *(const bf16x8*)(p_ + j * 1024);    \
  } while (0)
#define MFMA_Q32(mh_, nh_) do {                                                        \
    __builtin_amdgcn_s_setprio(1);                                                     \
    _Pragma("unroll")                                                                  \
    for (int i = 0; i < 4; i++)                                                        \
      _Pragma("unroll")                                                                \
      for (int j = 0; j < 2; j++)                                                      \
        acc[(mh_)*4 + i][(nh_)*2 + j] = __builtin_amdgcn_mfma_f32_16x16x32_bf16(       \
            af[i], bfr[(nh_)*2 + j], acc[(mh_)*4 + i][(nh_)*2 + j], 0, 0, 0);          \
    __builtin_amdgcn_s_setprio(0);                                                     \
  } while (0)
#define SBAR() do { __builtin_amdgcn_sched_barrier(0);                                 \
    __builtin_amdgcn_s_barrier(); __builtin_amdgcn_sched_barrier(0); } while (0)
#define LGKM0() do { asm volatile("s_waitcnt lgkmcnt(0)" ::: "memory");                \
    __builtin_amdgcn_sched_barrier(0); } while (0)

  // prologue: stage tile 0 (A0,B0,B1,A1 = 4 loads); A0,B0,B1 landed, A1 in flight
  STAGE_A32(0, 0, 0); STAGE_B32(0, 0, 0); STAGE_B32(1, 0, 0); STAGE_A32(1, 0, 0);
  asm volatile("s_waitcnt vmcnt(1)" ::: "memory");
  SBAR();

  for (int T = 0; T < NT; ++T) {
    const int cb = T & 1, nb = cb ^ 1;
    const int kk = (T + 1) << 5;
    const bool st = (T + 1 < NT);
    // P0: read A0,B0(T); stage A0,B0(T+1); MFMA q(0,0)
    LOAD_A32(0, cb); LOAD_B32(0, cb);
    if (st) { STAGE_A32(0, nb, kk); STAGE_B32(0, nb, kk); }
    SBAR(); LGKM0();
    MFMA_Q32(0, 0);
    if (st) asm volatile("s_waitcnt vmcnt(3)" ::: "memory");   // B1(T) landed
    else    asm volatile("s_waitcnt vmcnt(1)" ::: "memory");
    SBAR();
    // P1: read B1(T); stage B1(T+1); MFMA q(0,1)
    LOAD_B32(1, cb);
    if (st) STAGE_B32(1, nb, kk);
    SBAR(); LGKM0();
    MFMA_Q32(0, 1);
    if (st) asm volatile("s_waitcnt vmcnt(3)" ::: "memory");   // A1(T) landed
    else    asm volatile("s_waitcnt vmcnt(0)" ::: "memory");
    SBAR();
    // P2: read A1(T); stage A1(T+1); MFMA q(1,0)
    LOAD_A32(1, cb);
    if (st) STAGE_A32(1, nb, kk);
    SBAR(); LGKM0();
    MFMA_Q32(1, 0);
    SBAR();
    // P3: MFMA q(1,1)
    MFMA_Q32(1, 1);
    if (st) asm volatile("s_waitcnt vmcnt(2)" ::: "memory");   // A0,B0(T+1) landed
    SBAR();
  }
#undef STAGE_A32
#undef STAGE_B32
#undef LOAD_A32
#undef LOAD_B32
#undef MFMA_Q32
#undef SBAR
#undef LGKM0

  // SILU epilogue (identical acc layout to gemm8p)
  const int lq4 = lq * 4;
  #pragma unroll
  for (int mi = 0; mi < 8; mi++) {
    #pragma unroll
    for (int r = 0; r < 4; r++) {
      const long row = m0 + (mi >> 2) * 128 + wm2 * 64 + (mi & 3) * 16 + lq4 + r;
      #pragma unroll
      for (int nj = 0; nj < 2; nj++) {
        const long col = n0c + wn4 * 32 + nj * 16 + lr;
        float g = acc[mi][nj][r];
        float v = acc[mi][nj + 2][r];
        float sg = g / (1.0f + __expf(-g));
        ((__bf16*)Cv)[row * (long)ldc + col] = (__bf16)(sg * v);
      }
    }
  }
}

// ---------------- block-local flash attention v3 (round-3, verified) ----------------
__global__ __launch_bounds__(256) void attn_kernel(const __bf16* __restrict__ qkv,
                                                   __bf16* __restrict__ ctx) {
  const int qt   = blockIdx.x;
  const int head = blockIdx.y;
  const int b    = blockIdx.z;
  const int w    = threadIdx.x >> 6;
  const int lane = threadIdx.x & 63;
  const int lr = lane & 15;
  const int lq = lane >> 4;
  const int q0   = qt * 64;
  const int blk0 = q0 & ~511;
  const int nkv  = q0 + 64 - blk0;    // multiple of 64
  const int NT   = nkv >> 5;          // even
  const long tok0 = (long)b * SEQLEN;

  const int qrow = q0 + w * 16 + lr;
  const long qoff = (tok0 + qrow) * QKV_W + head * 64 + lq * 8;
  bf16x8 qf0 = *(const bf16x8*)(qkv + qoff);
  bf16x8 qf1 = *(const bf16x8*)(qkv + qoff + 32);

  __shared__ __align__(16) char VTb[8192];   // V^T: d-rows of 128B, 2 kv-halves of 4 chunks
  __shared__ __align__(16) char Pbb[8192];   // per-wave P: q-rows of 128B, 2 halves

  const __bf16* kp = qkv + (tok0 + blk0 + lr) * QKV_W + HID + head * 64 + lq * 8;
  const int skv = threadIdx.x & 31;
  const int sd0 = (threadIdx.x >> 5) * 8;
  const __bf16* vp = qkv + (tok0 + blk0 + skv) * QKV_W + 2 * HID + head * 64 + sd0;

  bf16x8 ka[2][2], kb[2][2];

#define LOADK(KN, tk) do { \
    KN[0][0] = *(const bf16x8*)(kp + (long)(tk) * QKV_W); \
    KN[0][1] = *(const bf16x8*)(kp + (long)(tk) * QKV_W + 32); \
    KN[1][0] = *(const bf16x8*)(kp + (long)((tk) + 16) * QKV_W); \
    KN[1][1] = *(const bf16x8*)(kp + (long)((tk) + 16) * QKV_W + 32); \
  } while (0)

#define WRITEV(vr_, hb_) do { \
    const int c_ = (hb_) * 4 + (skv >> 3); \
    char* vb_ = VTb + sd0 * 128 + ((skv & 7) * 2); \
    _Pragma("unroll") \
    for (int i_ = 0; i_ < 8; i_++) \
      *(__bf16*)(vb_ + i_ * 128 + ((c_ ^ i_) * 16)) = vr_[i_]; \
  } while (0)

  LOADK(ka, 0);
  {
    bf16x8 vr0 = *(const bf16x8*)(vp);
    WRITEV(vr0, 0);
  }
  __syncthreads();

  float m[4], l[4];
  f32x4 oacc[4] = {};
  #pragma unroll
  for (int r = 0; r < 4; r++) { m[r] = -1e30f; l[r] = 0.0f; }
  const int myrow = q0 + w * 16 + lq * 4;

#define ITER(t_, hb_, KC, KN) { \
    const int tkn_ = ((t_) + 1) * 32; \
    const bool more_ = ((t_) + 1 < NT); \
    bf16x8 vr_ = {}; \
    if (more_) { LOADK(KN, tkn_); vr_ = *(const bf16x8*)(vp + (long)tkn_ * QKV_W); } \
    f32x4 s0 = {0.f, 0.f, 0.f, 0.f}, s1 = {0.f, 0.f, 0.f, 0.f}; \
    s0 = __builtin_amdgcn_mfma_f32_16x16x32_bf16(qf0, KC[0][0], s0, 0, 0, 0); \
    s0 = __builtin_amdgcn_mfma_f32_16x16x32_bf16(qf1, KC[0][1], s0, 0, 0, 0); \
    s1 = __builtin_amdgcn_mfma_f32_16x16x32_bf16(qf0, KC[1][0], s1, 0, 0, 0); \
    s1 = __builtin_amdgcn_mfma_f32_16x16x32_bf16(qf1, KC[1][1], s1, 0, 0, 0); \
    const int kpos0_ = blk0 + (t_) * 32 + lr; \
    float p0[4], p1[4], alpha[4]; \
    _Pragma("unroll") \
    for (int r = 0; r < 4; r++) { \
      float v0 = s0[r] * 0.125f, v1 = s1[r] * 0.125f; \
      v0 = (kpos0_      <= myrow + r) ? v0 : -1e30f; \
      v1 = (kpos0_ + 16 <= myrow + r) ? v1 : -1e30f; \
      float mx = fmaxf(v0, v1); \
      mx = fmaxf(mx, __shfl_xor(mx, 1)); \
      mx = fmaxf(mx, __shfl_xor(mx, 2)); \
      mx = fmaxf(mx, __shfl_xor(mx, 4)); \
      mx = fmaxf(mx, __shfl_xor(mx, 8)); \
      float mn = fmaxf(m[r], mx); \
      alpha[r] = __expf(m[r] - mn); \
      m[r] = mn; \
      p0[r] = __expf(v0 - mn); \
      p1[r] = __expf(v1 - mn); \
      float rs = p0[r] + p1[r]; \
      rs += __shfl_xor(rs, 1); rs += __shfl_xor(rs, 2); \
      rs += __shfl_xor(rs, 4); rs += __shfl_xor(rs, 8); \
      l[r] = l[r] * alpha[r] + rs; \
    } \
    _Pragma("unroll") \
    for (int dt = 0; dt < 4; dt++) \
      _Pragma("unroll") \
      for (int r = 0; r < 4; r++) oacc[dt][r] *= alpha[r]; \
    { \
      char* pw_ = Pbb + w * 2048 + (lq * 4) * 128 + ((lr & 7) * 2); \
      const int cl_ = (hb_) * 4 + (lr >> 3); \
      _Pragma("unroll") \
      for (int r = 0; r < 4; r++) { \
        const int q7_ = (lq * 4 + r) & 7; \
        *(__bf16*)(pw_ + r * 128 + (((cl_    ) ^ q7_) * 16)) = (__bf16)p0[r]; \
        *(__bf16*)(pw_ + r * 128 + (((cl_ + 2) ^ q7_) * 16)) = (__bf16)p1[r]; \
      } \
    } \
    asm volatile("s_waitcnt lgkmcnt(0)" ::: "memory"); \
    const int swz_ = (((hb_) * 4 + lq) ^ (lr & 7)) * 16; \
    bf16x8 pf_ = *(const bf16x8*)(Pbb + w * 2048 + lr * 128 + swz_); \
    _Pragma("unroll") \
    for (int dt = 0; dt < 4; dt++) { \
      bf16x8 vf_ = *(const bf16x8*)(VTb + dt * 2048 + lr * 128 + swz_); \
      oacc[dt] = __builtin_amdgcn_mfma_f32_16x16x32_bf16(pf_, vf_, oacc[dt], 0, 0, 0); \
    } \
    __syncthreads(); \
    if (more_) WRITEV(vr_, (hb_) ^ 1); \
    __syncthreads(); \
  }

  for (int t2 = 0; t2 < NT; t2 += 2) {
    ITER(t2, 0, ka, kb)
    ITER(t2 + 1, 1, kb, ka)
  }
#undef ITER
#undef LOADK
#undef WRITEV

  #pragma unroll
  for (int r = 0; r < 4; r++) {
    float inv = 1.0f / l[r];
    long obase = (tok0 + myrow + r) * HID + head * 64;
    #pragma unroll
    for (int dt = 0; dt < 4; dt++)
      ctx[obase + dt * 16 + lr] = (__bf16)(oacc[dt][r] * inv);
  }
}

extern "C" void kernel_launch(void* const* d_in, const int* in_sizes, int n_in,
                              void* d_out, int out_size, void* d_ws, size_t ws_size,
                              hipStream_t stream) {
  const float* x      = (const float*)d_in[0];
  const float* anw    = (const float*)d_in[1];
  const float* fnw    = (const float*)d_in[2];
  const float* w_qkv  = (const float*)d_in[3];
  const float* w_o    = (const float*)d_in[4];
  const float* w_up   = (const float*)d_in[5];
  const float* w_down = (const float*)d_in[6];
  float* out = (float*)d_out;

  char* wsb = (char*)d_ws;
  __bf16* ABUF = (__bf16*)wsb;                        // 16 MiB: h1 / ctx / h2
  __bf16* QKV  = (__bf16*)(wsb + (size_t)16777216);   // 50.3 MiB: qkv; later act (33.5 MiB)
  __bf16* WBUF = (__bf16*)(wsb + (size_t)83886080);   // <=33.5 MiB: bf16 weight scratch
  __bf16* ACT  = QKV;                                  // reuse after attention

  // attention half
  rmsnorm_kernel<<<TOKENS, 256, 0, stream>>>(x, anw, ABUF);
  cvt_kernel<<<(QKV_W * HID / 4 + 255) / 256, 256, 0, stream>>>(w_qkv, WBUF, QKV_W * HID / 4);
  // Q,K (rope fused) via 8-phase BK=64: grid 16x16 = 256 blocks = exactly 1 round
  gemm8p<true, false><<<dim3(4096 / 256, TOKENS / 256), 512, 0, stream>>>(
      ABUF, HID, WBUF, HID, (void*)QKV, QKV_W, HID);
  // V (plain) via old kernel: grid 16x32 = 512 blocks, full chip
  gemm_bt<true, false, false, false><<<dim3(HID / 128, TOKENS / 128), 256, 0, stream>>>(
      ABUF, HID, WBUF + (size_t)4096 * HID, HID, (void*)(QKV + 4096), QKV_W, nullptr, HID);
  attn_kernel<<<dim3(SEQLEN / 64, 32, 2), 256, 0, stream>>>(QKV, ABUF);
  cvt_kernel<<<(HID * HID / 4 + 255) / 256, 256, 0, stream>>>(w_o, WBUF, HID * HID / 4);
  gemm_bt<false, true, false, false><<<dim3(HID / 128, TOKENS / 128), 256, 0, stream>>>(
      ABUF, HID, WBUF, HID, (void*)out, HID, x, HID);   // out = x + ctx@w_o^T

  // ffn half
  rmsnorm_kernel<<<TOKENS, 256, 0, stream>>>(out, fnw, ABUF);
  cvt_kernel<<<(UP_W * HID / 4 + 255) / 256, 256, 0, stream>>>(w_up, WBUF, UP_W * HID / 4);
  // fused up+silu via BK=32 2-blocks/CU kernel: 512 blocks ALL co-resident
  gemm_up32<<<dim3(INTER_ / 128, TOKENS / 256), 512, 0, stream>>>(
      ABUF, HID, WBUF, HID, (void*)ACT, INTER_, HID);
  cvt_kernel<<<(HID * INTER_ / 4 + 255) / 256, 256, 0, stream>>>(w_down, WBUF, HID * INTER_ / 4);
  gemm_bt<false, true, false, false><<<dim3(HID / 128, TOKENS / 128), 256, 0, stream>>>(
      ACT, INTER_, WBUF, INTER_, (void*)out, HID, out, INTER_); // out += act@w_down^T
}

// Round 9
// 563.378 us; speedup vs baseline: 2.5586x; 2.5586x over previous
//
#include <hip/hip_runtime.h>
#include <cstdint>
#include <cstddef>

typedef __bf16 bf16x8 __attribute__((ext_vector_type(8)));
typedef __bf16 bf16x4 __attribute__((ext_vector_type(4)));
typedef float  f32x4  __attribute__((ext_vector_type(4)));

#define TOKENS  4096
#define SEQLEN  2048
#define HID     2048
#define QKV_W   6144
#define UP_W    8192
#define INTER_  4096

__device__ __forceinline__ void async16(const void* g, void* l) {
  __builtin_amdgcn_global_load_lds(
      (__attribute__((address_space(1))) void*)(g),
      (__attribute__((address_space(3))) void*)(l), 16, 0, 0);
}

// ---------------- fp32 -> bf16 weight convert ----------------
__global__ __launch_bounds__(256) void cvt_kernel(const float* __restrict__ src,
                                                  __bf16* __restrict__ dst, int n4) {
  int i = blockIdx.x * 256 + threadIdx.x;
  if (i >= n4) return;
  float4 f = ((const float4*)src)[i];
  bf16x4 o;
  o[0] = (__bf16)f.x; o[1] = (__bf16)f.y; o[2] = (__bf16)f.z; o[3] = (__bf16)f.w;
  ((bf16x4*)dst)[i] = o;
}

// ---------------- rmsnorm: fp32 in -> bf16 out ----------------
__global__ __launch_bounds__(256) void rmsnorm_kernel(const float* __restrict__ x,
                                                      const float* __restrict__ wgt,
                                                      __bf16* __restrict__ out) {
  const int tok = blockIdx.x;
  const int t = threadIdx.x;
  const float4* xr = (const float4*)(x + (long)tok * HID);
  float4 a = xr[t], b = xr[t + 256];
  float ss = a.x*a.x + a.y*a.y + a.z*a.z + a.w*a.w
           + b.x*b.x + b.y*b.y + b.z*b.z + b.w*b.w;
  #pragma unroll
  for (int off = 32; off; off >>= 1) ss += __shfl_xor(ss, off);
  __shared__ float red[4];
  if ((t & 63) == 0) red[t >> 6] = ss;
  __syncthreads();
  float tot = red[0] + red[1] + red[2] + red[3];
  float r = rsqrtf(tot * (1.0f / HID) + 1e-5f);
  const float4* wr = (const float4*)wgt;
  float4 wa = wr[t], wb = wr[t + 256];
  bf16x4 o0, o1;
  o0[0] = (__bf16)(a.x * r * wa.x); o0[1] = (__bf16)(a.y * r * wa.y);
  o0[2] = (__bf16)(a.z * r * wa.z); o0[3] = (__bf16)(a.w * r * wa.w);
  o1[0] = (__bf16)(b.x * r * wb.x); o1[1] = (__bf16)(b.y * r * wb.y);
  o1[2] = (__bf16)(b.z * r * wb.z); o1[3] = (__bf16)(b.w * r * wb.w);
  bf16x4* orow = (bf16x4*)(out + (long)tok * HID);
  orow[t] = o0; orow[t + 256] = o1;
}

// ---------------- 8-phase 256x256 pipelined GEMM v3 (verified 983 TF) -- QK only ------
template<bool ROPE, bool SILU>
__global__ __launch_bounds__(512, 2) void gemm8p(const __bf16* __restrict__ A, int lda,
                                                 const __bf16* __restrict__ B, int ldb,
                                                 void* Cv, int ldc, int K) {
  __shared__ __align__(16) __bf16 As[2 * 16384];   // 2 x 32 KiB
  __shared__ __align__(16) __bf16 Bs[2 * 16384];   // 2 x 32 KiB
  const int tid  = threadIdx.x;
  const int lane = tid & 63;
  const int w    = tid >> 6;
  const int wm2  = w >> 2;        // 0..1
  const int wn4  = w & 3;         // 0..3
  const int lr   = lane & 15;
  const int lq   = lane >> 4;
  const int m0   = blockIdx.y * 256;
  const int n0   = ROPE ? blockIdx.x * 256 : 0;
  const int n0c  = SILU ? blockIdx.x * 128 : 0;

  const long r0 = tid >> 3;
  const int  e  = (((tid & 7) ^ ((int)r0 & 7)) * 8);
  const __bf16* Ap0 = A + (long)(m0 + r0) * lda + e;
  long br0, br1, bhs;
  if (ROPE) {
    br0 = n0 + 64 * (((int)r0 >> 5) & 3) + ((int)r0 & 31);
    br1 = n0 + 64 * ((((int)r0 + 64) >> 5) & 3) + ((int)r0 & 31);
    bhs = 32 * (long)ldb;
  } else {
    br0 = n0c + r0;
    br1 = n0c + r0 + 64;
    bhs = (long)INTER_ * ldb;
  }
  const __bf16* Bp0 = B + br0 * ldb + e;
  const __bf16* Bp1 = B + br1 * ldb + e;
  char* sA = (char*)As;
  char* sB = (char*)Bs;
  const int tid16 = tid * 16;

#define STAGE_A(h_, nb_, kk_) do {                                                     \
    async16(Ap0 + (long)((h_) * 128) * lda + (kk_),      sA + (nb_)*32768 + (h_)*16384 + tid16);        \
    async16(Ap0 + (long)((h_) * 128 + 64) * lda + (kk_), sA + (nb_)*32768 + (h_)*16384 + 8192 + tid16); \
  } while (0)
#define STAGE_B(h_, nb_, kk_) do {                                                     \
    async16(Bp0 + (h_) * bhs + (kk_), sB + (nb_)*32768 + (h_)*16384 + tid16);          \
    async16(Bp1 + (h_) * bhs + (kk_), sB + (nb_)*32768 + (h_)*16384 + 8192 + tid16);   \
  } while (0)

  const int ch0 = ((lq ^ (lr & 7)) * 16);
  const int ch1 = (((4 + lq) ^ (lr & 7)) * 16);
  const int abase = (wm2 * 64 + lr) * 128;
  const int bbase = (wn4 * 32 + lr) * 128;

  f32x4 acc[8][4] = {};
  bf16x8 af[4][2], bfr[4][2];
  const int NT = K >> 6;

#define LOAD_A(mh_) do {                                                               \
    _Pragma("unroll")                                                                  \
    for (int i = 0; i < 4; i++) {                                                      \
      af[i][0] = *(const bf16x8*)(Ab + abase + (mh_)*16384 + i*2048 + ch0);            \
      af[i][1] = *(const bf16x8*)(Ab + abase + (mh_)*16384 + i*2048 + ch1);            \
    } } while (0)
#define LOAD_B(nh_) do {                                                               \
    _Pragma("unroll")                                                                  \
    for (int j = 0; j < 2; j++) {                                                      \
      bfr[(nh_)*2 + j][0] = *(const bf16x8*)(Bb + bbase + (nh_)*16384 + j*2048 + ch0); \
      bfr[(nh_)*2 + j][1] = *(const bf16x8*)(Bb + bbase + (nh_)*16384 + j*2048 + ch1); \
    } } while (0)
#define MFMA_Q(mh_, nh_) do {                                                          \
    __builtin_amdgcn_s_setprio(1);                                                     \
    _Pragma("unroll")                                                                  \
    for (int ks = 0; ks < 2; ks++)                                                     \
      _Pragma("unroll")                                                                \
      for (int i = 0; i < 4; i++)                                                      \
        _Pragma("unroll")                                                              \
        for (int j = 0; j < 2; j++)                                                    \
          acc[(mh_)*4 + i][(nh_)*2 + j] = __builtin_amdgcn_mfma_f32_16x16x32_bf16(     \
              af[i][ks], bfr[(nh_)*2 + j][ks], acc[(mh_)*4 + i][(nh_)*2 + j], 0, 0, 0);\
    __builtin_amdgcn_s_setprio(0);                                                     \
  } while (0)
#define SBAR() do { __builtin_amdgcn_sched_barrier(0);                                 \
    __builtin_amdgcn_s_barrier(); __builtin_amdgcn_sched_barrier(0); } while (0)
#define LGKM0() do { asm volatile("s_waitcnt lgkmcnt(0)" ::: "memory");                \
    __builtin_amdgcn_sched_barrier(0); } while (0)

  STAGE_A(0, 0, 0); STAGE_B(0, 0, 0); STAGE_B(1, 0, 0); STAGE_A(1, 0, 0);
  asm volatile("s_waitcnt vmcnt(4)" ::: "memory");
  SBAR();

  for (int T = 0; T < NT; ++T) {
    const int cb = T & 1, nb = cb ^ 1;
    const int kk = (T + 1) << 6;
    const bool st = (T + 1 < NT);
    const char* Ab = (const char*)As + cb * 32768;
    const char* Bb = (const char*)Bs + cb * 32768;
    LOAD_A(0); LOAD_B(0);
    if (st) { STAGE_A(0, nb, kk); STAGE_B(0, nb, kk); }
    SBAR(); LGKM0();
    MFMA_Q(0, 0);
    if (st) asm volatile("s_waitcnt vmcnt(6)" ::: "memory");
    else    asm volatile("s_waitcnt vmcnt(2)" ::: "memory");
    SBAR();
    LOAD_B(1);
    if (st) STAGE_B(1, nb, kk);
    SBAR(); LGKM0();
    MFMA_Q(0, 1);
    if (st) asm volatile("s_waitcnt vmcnt(6)" ::: "memory");
    else    asm volatile("s_waitcnt vmcnt(0)" ::: "memory");
    SBAR();
    LOAD_A(1);
    if (st) STAGE_A(1, nb, kk);
    SBAR(); LGKM0();
    MFMA_Q(1, 0);
    SBAR();
    MFMA_Q(1, 1);
    if (st) asm volatile("s_waitcnt vmcnt(4)" ::: "memory");
    SBAR();
  }
#undef STAGE_A
#undef STAGE_B
#undef LOAD_A
#undef LOAD_B
#undef MFMA_Q
#undef SBAR
#undef LGKM0

  const int lq4 = lq * 4;
  if (ROPE) {
    if (n0 < 4096) {
      const float invf0 = exp2f((float)(lr)      * -0.41524101186092029f);
      const float invf1 = exp2f((float)(16 + lr) * -0.41524101186092029f);
      #pragma unroll
      for (int mi = 0; mi < 8; mi++) {
        #pragma unroll
        for (int r = 0; r < 4; r++) {
          const long row = m0 + (mi >> 2) * 128 + wm2 * 64 + (mi & 3) * 16 + lq4 + r;
          const float s = (float)(int)(row & (SEQLEN - 1));
          __bf16* crow = (__bf16*)Cv + row * (long)ldc + n0 + wn4 * 64 + lr;
          #pragma unroll
          for (int nj = 0; nj < 2; nj++) {
            float x1 = acc[mi][nj][r], x2 = acc[mi][nj + 2][r];
            float ang = s * (nj ? invf1 : invf0);
            float sn, cs;
            __sincosf(ang, &sn, &cs);
            crow[nj * 16]      = (__bf16)(x1 * cs - x2 * sn);
            crow[nj * 16 + 32] = (__bf16)(x2 * cs + x1 * sn);
          }
        }
      }
    } else {
      #pragma unroll
      for (int mi = 0; mi < 8; mi++) {
        #pragma unroll
        for (int r = 0; r < 4; r++) {
          const long row = m0 + (mi >> 2) * 128 + wm2 * 64 + (mi & 3) * 16 + lq4 + r;
          __bf16* crow = (__bf16*)Cv + row * (long)ldc + n0 + wn4 * 64 + lr;
          #pragma unroll
          for (int njf = 0; njf < 4; njf++)
            crow[(njf >> 1) * 32 + (njf & 1) * 16] = (__bf16)acc[mi][njf][r];
        }
      }
    }
  } else {  // SILU (unused instantiation path kept for template completeness)
    #pragma unroll
    for (int mi = 0; mi < 8; mi++) {
      #pragma unroll
      for (int r = 0; r < 4; r++) {
        const long row = m0 + (mi >> 2) * 128 + wm2 * 64 + (mi & 3) * 16 + lq4 + r;
        #pragma unroll
        for (int nj = 0; nj < 2; nj++) {
          const long col = n0c + wn4 * 32 + nj * 16 + lr;
          float g = acc[mi][nj][r];
          float v = acc[mi][nj + 2][r];
          float sg = g / (1.0f + __expf(-g));
          ((__bf16*)Cv)[row * (long)ldc + col] = (__bf16)(sg * v);
        }
      }
    }
  }
}

// ---------------- gemm4w: 128x128 tile, 4 waves, v3 4-phase schedule, 64KiB LDS ------
// 2 blocks/CU (launch_bounds(256,2): 8 waves/CU = 2 waves/SIMD -> 256-reg budget).
// ROUND-8 BUG FIX: bfr must hold BOTH B-halves across the quadrant sequence
// (q(1,0) consumes B0 *after* B1 was loaded) -> bfr[4][2] indexed bfr[nh*2+j],
// exactly v3's register discipline. af[2][2] is safe (A0 fully consumed before P2).
// vmcnt accounting identical to v3 (same per-half load counts): prologue 4;
// steady 6/6/-/4; tail 2/0. Invariant at tile start: {B1(T),A1(T)} = 4 outstanding.
template<bool OUT_BF16, bool ADD_RES, bool SILU>
__global__ __launch_bounds__(256, 2) void gemm4w(const __bf16* __restrict__ A, int lda,
                                                 const __bf16* __restrict__ B, int ldb,
                                                 void* Cv, int ldc,
                                                 const float* __restrict__ Res, int K) {
  __shared__ __align__(16) __bf16 As[2 * 8192];   // 2 buf x 16 KiB
  __shared__ __align__(16) __bf16 Bs[2 * 8192];   // 2 buf x 16 KiB
  const int tid  = threadIdx.x;
  const int lane = tid & 63;
  const int w    = tid >> 6;      // 0..3
  const int wm1  = w >> 1;        // 0..1
  const int wn1  = w & 1;         // 0..1
  const int lr   = lane & 15;
  const int lq   = lane >> 4;
  const int m0   = blockIdx.y * 128;
  const int n0   = SILU ? 0 : blockIdx.x * 128;
  const int n0c  = SILU ? blockIdx.x * 64 : 0;

  const int r0 = tid >> 3;                         // 0..31
  const int e  = (((tid & 7) ^ (r0 & 7)) * 8);     // swizzled element offset
  const __bf16* ApS = A + (long)(m0 + r0) * lda + e;
  long br0, bhs;
  if (SILU) { br0 = n0c + r0; bhs = (long)INTER_ * ldb; }
  else      { br0 = n0 + r0;  bhs = 64 * (long)ldb; }
  const __bf16* BpS = B + br0 * ldb + e;
  char* sA = (char*)As;
  char* sB = (char*)Bs;
  const int tid16 = tid * 16;

#define STAGE_A(h_, nb_, kk_) do {                                                       \
    async16(ApS + (long)((h_) * 64) * lda + (kk_),      sA + (nb_)*16384 + (h_)*8192 + tid16);        \
    async16(ApS + (long)((h_) * 64 + 32) * lda + (kk_), sA + (nb_)*16384 + (h_)*8192 + 4096 + tid16); \
  } while (0)
#define STAGE_B(h_, nb_, kk_) do {                                                       \
    async16(BpS + (h_) * bhs + (kk_),                   sB + (nb_)*16384 + (h_)*8192 + tid16);        \
    async16(BpS + (h_) * bhs + 32 * (long)ldb + (kk_),  sB + (nb_)*16384 + (h_)*8192 + 4096 + tid16); \
  } while (0)

  const int ch0 = ((lq ^ (lr & 7)) * 16);
  const int ch1 = (((4 + lq) ^ (lr & 7)) * 16);
  const int abase = (wm1 * 32 + lr) * 128;   // + mh*8192 + i*2048 + ch{ks}
  const int bbase = (wn1 * 32 + lr) * 128;   // + nh*8192 + j*2048 + ch{ks}

  f32x4 acc[4][4] = {};
  bf16x8 af[2][2], bfr[4][2];
  const int NT = K >> 6;

#define LOAD_A(mh_) do {                                                                 \
    _Pragma("unroll")                                                                    \
    for (int i = 0; i < 2; i++) {                                                        \
      af[i][0] = *(const bf16x8*)(Ab + abase + (mh_)*8192 + i*2048 + ch0);               \
      af[i][1] = *(const bf16x8*)(Ab + abase + (mh_)*8192 + i*2048 + ch1);               \
    } } while (0)
#define LOAD_B(nh_) do {                                                                 \
    _Pragma("unroll")                                                                    \
    for (int j = 0; j < 2; j++) {                                                        \
      bfr[(nh_)*2 + j][0] = *(const bf16x8*)(Bb + bbase + (nh_)*8192 + j*2048 + ch0);    \
      bfr[(nh_)*2 + j][1] = *(const bf16x8*)(Bb + bbase + (nh_)*8192 + j*2048 + ch1);    \
    } } while (0)
#define MFMA_Q(mh_, nh_) do {                                                            \
    __builtin_amdgcn_s_setprio(1);                                                       \
    _Pragma("unroll")                                                                    \
    for (int ks = 0; ks < 2; ks++)                                                       \
      _Pragma("unroll")                                                                  \
      for (int i = 0; i < 2; i++)                                                        \
        _Pragma("unroll")                                                                \
        for (int j = 0; j < 2; j++)                                                      \
          acc[(mh_)*2 + i][(nh_)*2 + j] = __builtin_amdgcn_mfma_f32_16x16x32_bf16(       \
              af[i][ks], bfr[(nh_)*2 + j][ks], acc[(mh_)*2 + i][(nh_)*2 + j], 0, 0, 0);  \
    __builtin_amdgcn_s_setprio(0);                                                       \
  } while (0)
#define SBAR() do { __builtin_amdgcn_sched_barrier(0);                                   \
    __builtin_amdgcn_s_barrier(); __builtin_amdgcn_sched_barrier(0); } while (0)
#define LGKM0() do { asm volatile("s_waitcnt lgkmcnt(0)" ::: "memory");                  \
    __builtin_amdgcn_sched_barrier(0); } while (0)

  // prologue: stage tile 0 (A0,B0,B1,A1 = 8 loads); wait A0,B0 landed (B1,A1 in flight)
  STAGE_A(0, 0, 0); STAGE_B(0, 0, 0); STAGE_B(1, 0, 0); STAGE_A(1, 0, 0);
  asm volatile("s_waitcnt vmcnt(4)" ::: "memory");
  SBAR();

  for (int T = 0; T < NT; ++T) {
    const int cb = T & 1, nb = cb ^ 1;
    const int kk = (T + 1) << 6;
    const bool st = (T + 1 < NT);
    const char* Ab = (const char*)As + cb * 16384;
    const char* Bb = (const char*)Bs + cb * 16384;
    // P0: read A0,B0(T); stage A0,B0(T+1); MFMA q(0,0)
    LOAD_A(0); LOAD_B(0);
    if (st) { STAGE_A(0, nb, kk); STAGE_B(0, nb, kk); }
    SBAR(); LGKM0();
    MFMA_Q(0, 0);
    if (st) asm volatile("s_waitcnt vmcnt(6)" ::: "memory");   // B1(T) landed
    else    asm volatile("s_waitcnt vmcnt(2)" ::: "memory");
    SBAR();
    // P1: read B1(T); stage B1(T+1); MFMA q(0,1)
    LOAD_B(1);
    if (st) STAGE_B(1, nb, kk);
    SBAR(); LGKM0();
    MFMA_Q(0, 1);
    if (st) asm volatile("s_waitcnt vmcnt(6)" ::: "memory");   // A1(T) landed
    else    asm volatile("s_waitcnt vmcnt(0)" ::: "memory");
    SBAR();
    // P2: read A1(T); stage A1(T+1); MFMA q(1,0)
    LOAD_A(1);
    if (st) STAGE_A(1, nb, kk);
    SBAR(); LGKM0();
    MFMA_Q(1, 0);
    SBAR();
    // P3: MFMA q(1,1)
    MFMA_Q(1, 1);
    if (st) asm volatile("s_waitcnt vmcnt(4)" ::: "memory");   // A0,B0(T+1) landed
    SBAR();
  }
#undef STAGE_A
#undef STAGE_B
#undef LOAD_A
#undef LOAD_B
#undef MFMA_Q
#undef SBAR
#undef LGKM0

  const int lq4 = lq * 4;
  if (SILU) {
    #pragma unroll
    for (int mi = 0; mi < 4; mi++) {
      #pragma unroll
      for (int r = 0; r < 4; r++) {
        const long row = m0 + (mi >> 1) * 64 + wm1 * 32 + (mi & 1) * 16 + lq4 + r;
        #pragma unroll
        for (int nj = 0; nj < 2; nj++) {
          const long col = n0c + wn1 * 32 + nj * 16 + lr;
          float g = acc[mi][nj][r];
          float v = acc[mi][nj + 2][r];
          float sg = g / (1.0f + __expf(-g));
          ((__bf16*)Cv)[row * (long)ldc + col] = (__bf16)(sg * v);
        }
      }
    }
  } else {
    #pragma unroll
    for (int mi = 0; mi < 4; mi++) {
      #pragma unroll
      for (int r = 0; r < 4; r++) {
        const long row = m0 + (mi >> 1) * 64 + wm1 * 32 + (mi & 1) * 16 + lq4 + r;
        #pragma unroll
        for (int nj = 0; nj < 4; nj++) {
          const long col = n0 + (nj >> 1) * 64 + wn1 * 32 + (nj & 1) * 16 + lr;
          float v = acc[mi][nj][r];
          if (ADD_RES) v += Res[row * (long)ldc + col];
          if (OUT_BF16) ((__bf16*)Cv)[row * (long)ldc + col] = (__bf16)v;
          else          ((float*)Cv)[row * (long)ldc + col] = v;
        }
      }
    }
  }
}

// ---------------- block-local flash attention v3 (round-3, verified) ----------------
__global__ __launch_bounds__(256) void attn_kernel(const __bf16* __restrict__ qkv,
                                                   __bf16* __restrict__ ctx) {
  const int qt   = blockIdx.x;
  const int head = blockIdx.y;
  const int b    = blockIdx.z;
  const int w    = threadIdx.x >> 6;
  const int lane = threadIdx.x & 63;
  const int lr = lane & 15;
  const int lq = lane >> 4;
  const int q0   = qt * 64;
  const int blk0 = q0 & ~511;
  const int nkv  = q0 + 64 - blk0;    // multiple of 64
  const int NT   = nkv >> 5;          // even
  const long tok0 = (long)b * SEQLEN;

  const int qrow = q0 + w * 16 + lr;
  const long qoff = (tok0 + qrow) * QKV_W + head * 64 + lq * 8;
  bf16x8 qf0 = *(const bf16x8*)(qkv + qoff);
  bf16x8 qf1 = *(const bf16x8*)(qkv + qoff + 32);

  __shared__ __align__(16) char VTb[8192];   // V^T: d-rows of 128B, 2 kv-halves of 4 chunks
  __shared__ __align__(16) char Pbb[8192];   // per-wave P: q-rows of 128B, 2 halves

  const __bf16* kp = qkv + (tok0 + blk0 + lr) * QKV_W + HID + head * 64 + lq * 8;
  const int skv = threadIdx.x & 31;
  const int sd0 = (threadIdx.x >> 5) * 8;
  const __bf16* vp = qkv + (tok0 + blk0 + skv) * QKV_W + 2 * HID + head * 64 + sd0;

  bf16x8 ka[2][2], kb[2][2];

#define LOADK(KN, tk) do { \
    KN[0][0] = *(const bf16x8*)(kp + (long)(tk) * QKV_W); \
    KN[0][1] = *(const bf16x8*)(kp + (long)(tk) * QKV_W + 32); \
    KN[1][0] = *(const bf16x8*)(kp + (long)((tk) + 16) * QKV_W); \
    KN[1][1] = *(const bf16x8*)(kp + (long)((tk) + 16) * QKV_W + 32); \
  } while (0)

#define WRITEV(vr_, hb_) do { \
    const int c_ = (hb_) * 4 + (skv >> 3); \
    char* vb_ = VTb + sd0 * 128 + ((skv & 7) * 2); \
    _Pragma("unroll") \
    for (int i_ = 0; i_ < 8; i_++) \
      *(__bf16*)(vb_ + i_ * 128 + ((c_ ^ i_) * 16)) = vr_[i_]; \
  } while (0)

  LOADK(ka, 0);
  {
    bf16x8 vr0 = *(const bf16x8*)(vp);
    WRITEV(vr0, 0);
  }
  __syncthreads();

  float m[4], l[4];
  f32x4 oacc[4] = {};
  #pragma unroll
  for (int r = 0; r < 4; r++) { m[r] = -1e30f; l[r] = 0.0f; }
  const int myrow = q0 + w * 16 + lq * 4;

#define ITER(t_, hb_, KC, KN) { \
    const int tkn_ = ((t_) + 1) * 32; \
    const bool more_ = ((t_) + 1 < NT); \
    bf16x8 vr_ = {}; \
    if (more_) { LOADK(KN, tkn_); vr_ = *(const bf16x8*)(vp + (long)tkn_ * QKV_W); } \
    f32x4 s0 = {0.f, 0.f, 0.f, 0.f}, s1 = {0.f, 0.f, 0.f, 0.f}; \
    s0 = __builtin_amdgcn_mfma_f32_16x16x32_bf16(qf0, KC[0][0], s0, 0, 0, 0); \
    s0 = __builtin_amdgcn_mfma_f32_16x16x32_bf16(qf1, KC[0][1], s0, 0, 0, 0); \
    s1 = __builtin_amdgcn_mfma_f32_16x16x32_bf16(qf0, KC[1][0], s1, 0, 0, 0); \
    s1 = __builtin_amdgcn_mfma_f32_16x16x32_bf16(qf1, KC[1][1], s1, 0, 0, 0); \
    const int kpos0_ = blk0 + (t_) * 32 + lr; \
    float p0[4], p1[4], alpha[4]; \
    _Pragma("unroll") \
    for (int r = 0; r < 4; r++) { \
      float v0 = s0[r] * 0.125f, v1 = s1[r] * 0.125f; \
      v0 = (kpos0_      <= myrow + r) ? v0 : -1e30f; \
      v1 = (kpos0_ + 16 <= myrow + r) ? v1 : -1e30f; \
      float mx = fmaxf(v0, v1); \
      mx = fmaxf(mx, __shfl_xor(mx, 1)); \
      mx = fmaxf(mx, __shfl_xor(mx, 2)); \
      mx = fmaxf(mx, __shfl_xor(mx, 4)); \
      mx = fmaxf(mx, __shfl_xor(mx, 8)); \
      float mn = fmaxf(m[r], mx); \
      alpha[r] = __expf(m[r] - mn); \
      m[r] = mn; \
      p0[r] = __expf(v0 - mn); \
      p1[r] = __expf(v1 - mn); \
      float rs = p0[r] + p1[r]; \
      rs += __shfl_xor(rs, 1); rs += __shfl_xor(rs, 2); \
      rs += __shfl_xor(rs, 4); rs += __shfl_xor(rs, 8); \
      l[r] = l[r] * alpha[r] + rs; \
    } \
    _Pragma("unroll") \
    for (int dt = 0; dt < 4; dt++) \
      _Pragma("unroll") \
      for (int r = 0; r < 4; r++) oacc[dt][r] *= alpha[r]; \
    { \
      char* pw_ = Pbb + w * 2048 + (lq * 4) * 128 + ((lr & 7) * 2); \
      const int cl_ = (hb_) * 4 + (lr >> 3); \
      _Pragma("unroll") \
      for (int r = 0; r < 4; r++) { \
        const int q7_ = (lq * 4 + r) & 7; \
        *(__bf16*)(pw_ + r * 128 + (((cl_    ) ^ q7_) * 16)) = (__bf16)p0[r]; \
        *(__bf16*)(pw_ + r * 128 + (((cl_ + 2) ^ q7_) * 16)) = (__bf16)p1[r]; \
      } \
    } \
    asm volatile("s_waitcnt lgkmcnt(0)" ::: "memory"); \
    const int swz_ = (((hb_) * 4 + lq) ^ (lr & 7)) * 16; \
    bf16x8 pf_ = *(const bf16x8*)(Pbb + w * 2048 + lr * 128 + swz_); \
    _Pragma("unroll") \
    for (int dt = 0; dt < 4; dt++) { \
      bf16x8 vf_ = *(const bf16x8*)(VTb + dt * 2048 + lr * 128 + swz_); \
      oacc[dt] = __builtin_amdgcn_mfma_f32_16x16x32_bf16(pf_, vf_, oacc[dt], 0, 0, 0); \
    } \
    __syncthreads(); \
    if (more_) WRITEV(vr_, (hb_) ^ 1); \
    __syncthreads(); \
  }

  for (int t2 = 0; t2 < NT; t2 += 2) {
    ITER(t2, 0, ka, kb)
    ITER(t2 + 1, 1, kb, ka)
  }
#undef ITER
#undef LOADK
#undef WRITEV

  #pragma unroll
  for (int r = 0; r < 4; r++) {
    float inv = 1.0f / l[r];
    long obase = (tok0 + myrow + r) * HID + head * 64;
    #pragma unroll
    for (int dt = 0; dt < 4; dt++)
      ctx[obase + dt * 16 + lr] = (__bf16)(oacc[dt][r] * inv);
  }
}

extern "C" void kernel_launch(void* const* d_in, const int* in_sizes, int n_in,
                              void* d_out, int out_size, void* d_ws, size_t ws_size,
                              hipStream_t stream) {
  const float* x      = (const float*)d_in[0];
  const float* anw    = (const float*)d_in[1];
  const float* fnw    = (const float*)d_in[2];
  const float* w_qkv  = (const float*)d_in[3];
  const float* w_o    = (const float*)d_in[4];
  const float* w_up   = (const float*)d_in[5];
  const float* w_down = (const float*)d_in[6];
  float* out = (float*)d_out;

  char* wsb = (char*)d_ws;
  __bf16* ABUF = (__bf16*)wsb;                        // 16 MiB: h1 / ctx / h2
  __bf16* QKV  = (__bf16*)(wsb + (size_t)16777216);   // 50.3 MiB: qkv; later act (33.5 MiB)
  __bf16* WBUF = (__bf16*)(wsb + (size_t)83886080);   // <=33.5 MiB: bf16 weight scratch
  __bf16* ACT  = QKV;                                  // reuse after attention

  // attention half
  rmsnorm_kernel<<<TOKENS, 256, 0, stream>>>(x, anw, ABUF);
  cvt_kernel<<<(QKV_W * HID / 4 + 255) / 256, 256, 0, stream>>>(w_qkv, WBUF, QKV_W * HID / 4);
  // Q,K (rope fused) via 8-phase BK=64: grid 16x16 = 256 blocks = exactly 1 round
  gemm8p<true, false><<<dim3(4096 / 256, TOKENS / 256), 512, 0, stream>>>(
      ABUF, HID, WBUF, HID, (void*)QKV, QKV_W, HID);
  // V via gemm4w: grid 16x32 = 512 blocks, 2/CU -> 1 round
  gemm4w<true, false, false><<<dim3(HID / 128, TOKENS / 128), 256, 0, stream>>>(
      ABUF, HID, WBUF + (size_t)4096 * HID, HID, (void*)(QKV + 4096), QKV_W, nullptr, HID);
  attn_kernel<<<dim3(SEQLEN / 64, 32, 2), 256, 0, stream>>>(QKV, ABUF);
  cvt_kernel<<<(HID * HID / 4 + 255) / 256, 256, 0, stream>>>(w_o, WBUF, HID * HID / 4);
  // O via gemm4w (+residual, fp32 out): 512 blocks, 1 round
  gemm4w<false, true, false><<<dim3(HID / 128, TOKENS / 128), 256, 0, stream>>>(
      ABUF, HID, WBUF, HID, (void*)out, HID, x, HID);

  // ffn half
  rmsnorm_kernel<<<TOKENS, 256, 0, stream>>>(out, fnw, ABUF);
  cvt_kernel<<<(UP_W * HID / 4 + 255) / 256, 256, 0, stream>>>(w_up, WBUF, UP_W * HID / 4);
  // fused up+silu via gemm4w: grid 64x32 = 2048 blocks = 4 exact rounds at 2/CU
  gemm4w<true, false, true><<<dim3(INTER_ / 64, TOKENS / 128), 256, 0, stream>>>(
      ABUF, HID, WBUF, HID, (void*)ACT, INTER_, nullptr, HID);
  cvt_kernel<<<(HID * INTER_ / 4 + 255) / 256, 256, 0, stream>>>(w_down, WBUF, HID * INTER_ / 4);
  // down via gemm4w (+residual, fp32 out): 512 blocks, 1 round
  gemm4w<false, true, false><<<dim3(HID / 128, TOKENS / 128), 256, 0, stream>>>(
      ACT, INTER_, WBUF, INTER_, (void*)out, HID, out, INTER_);
}

// Round 10
// 560.093 us; speedup vs baseline: 2.5736x; 1.0059x over previous
//
#include <hip/hip_runtime.h>
#include <cstdint>
#include <cstddef>

typedef __bf16 bf16x8 __attribute__((ext_vector_type(8)));
typedef __bf16 bf16x4 __attribute__((ext_vector_type(4)));
typedef float  f32x4  __attribute__((ext_vector_type(4)));

#define TOKENS  4096
#define SEQLEN  2048
#define HID     2048
#define QKV_W   6144
#define UP_W    8192
#define INTER_  4096

__device__ __forceinline__ void async16(const void* g, void* l) {
  __builtin_amdgcn_global_load_lds(
      (__attribute__((address_space(1))) void*)(g),
      (__attribute__((address_space(3))) void*)(l), 16, 0, 0);
}

// ---------------- fp32 -> bf16 weight convert ----------------
__global__ __launch_bounds__(256) void cvt_kernel(const float* __restrict__ src,
                                                  __bf16* __restrict__ dst, int n4) {
  int i = blockIdx.x * 256 + threadIdx.x;
  if (i >= n4) return;
  float4 f = ((const float4*)src)[i];
  bf16x4 o;
  o[0] = (__bf16)f.x; o[1] = (__bf16)f.y; o[2] = (__bf16)f.z; o[3] = (__bf16)f.w;
  ((bf16x4*)dst)[i] = o;
}

// ---------------- rmsnorm: fp32 in -> bf16 out ----------------
__global__ __launch_bounds__(256) void rmsnorm_kernel(const float* __restrict__ x,
                                                      const float* __restrict__ wgt,
                                                      __bf16* __restrict__ out) {
  const int tok = blockIdx.x;
  const int t = threadIdx.x;
  const float4* xr = (const float4*)(x + (long)tok * HID);
  float4 a = xr[t], b = xr[t + 256];
  float ss = a.x*a.x + a.y*a.y + a.z*a.z + a.w*a.w
           + b.x*b.x + b.y*b.y + b.z*b.z + b.w*b.w;
  #pragma unroll
  for (int off = 32; off; off >>= 1) ss += __shfl_xor(ss, off);
  __shared__ float red[4];
  if ((t & 63) == 0) red[t >> 6] = ss;
  __syncthreads();
  float tot = red[0] + red[1] + red[2] + red[3];
  float r = rsqrtf(tot * (1.0f / HID) + 1e-5f);
  const float4* wr = (const float4*)wgt;
  float4 wa = wr[t], wb = wr[t + 256];
  bf16x4 o0, o1;
  o0[0] = (__bf16)(a.x * r * wa.x); o0[1] = (__bf16)(a.y * r * wa.y);
  o0[2] = (__bf16)(a.z * r * wa.z); o0[3] = (__bf16)(a.w * r * wa.w);
  o1[0] = (__bf16)(b.x * r * wb.x); o1[1] = (__bf16)(b.y * r * wb.y);
  o1[2] = (__bf16)(b.z * r * wb.z); o1[3] = (__bf16)(b.w * r * wb.w);
  bf16x4* orow = (bf16x4*)(out + (long)tok * HID);
  orow[t] = o0; orow[t + 256] = o1;
}

// ---------------- OLD BK=64 bf16 GEMM (round-0, verified) -- O, Down, V-proj ----
template<bool OUT_BF16, bool ADD_RES, bool ROPE, bool SILU>
__global__ __launch_bounds__(256) void gemm_bt(const __bf16* __restrict__ A, int lda,
                                               const __bf16* __restrict__ B, int ldb,
                                               void* Cv, int ldc,
                                               const float* __restrict__ Res, int K) {
  __shared__ __align__(16) __bf16 As[128 * 64];
  __shared__ __align__(16) __bf16 Bs[128 * 64];
  const int t = threadIdx.x;
  const int lane = t & 63;
  const int w = t >> 6;
  const int wm = (w >> 1) * 64, wn = (w & 1) * 64;
  const int m0 = blockIdx.y * 128;
  const int n0 = SILU ? blockIdx.x * 64 : blockIdx.x * 128;
  const int sr = t >> 3;
  const int sc = (((t & 7) ^ (sr & 7)) * 8);
  const __bf16* Ag = A + (long)(m0 + sr) * lda + sc;
  const __bf16* Bg = B + (long)(n0 + sr) * ldb + sc;
  char* lA = (char*)As + t * 16;
  char* lB = (char*)Bs + t * 16;
  const int lr = lane & 15;
  const int lq = lane >> 4;
  f32x4 acc[4][4] = {};
  for (int k0 = 0; k0 < K; k0 += 64) {
    __syncthreads();
    #pragma unroll
    for (int c = 0; c < 4; c++)
      async16(Ag + (long)(c * 32) * lda + k0, lA + c * 4096);
    #pragma unroll
    for (int c = 0; c < 4; c++) {
      const long rowoff = SILU ? (long)((c & 1) * INTER_ + (c >> 1) * 32) * ldb
                               : (long)(c * 32) * ldb;
      async16(Bg + rowoff + k0, lB + c * 4096);
    }
    __syncthreads();
    #pragma unroll
    for (int ks = 0; ks < 2; ks++) {
      const int pos = (((ks * 4 + lq) ^ (lr & 7)) * 8);
      bf16x8 af[4], bfr[4];
      #pragma unroll
      for (int i = 0; i < 4; i++)
        af[i]  = *(const bf16x8*)(As + (wm + i * 16 + lr) * 64 + pos);
      #pragma unroll
      for (int j = 0; j < 4; j++)
        bfr[j] = *(const bf16x8*)(Bs + (wn + j * 16 + lr) * 64 + pos);
      #pragma unroll
      for (int i = 0; i < 4; i++)
        #pragma unroll
        for (int j = 0; j < 4; j++)
          acc[i][j] = __builtin_amdgcn_mfma_f32_16x16x32_bf16(af[i], bfr[j], acc[i][j], 0, 0, 0);
    }
  }
  const int lq4 = lq * 4;
  #pragma unroll
  for (int i = 0; i < 4; i++) {
    #pragma unroll
    for (int r = 0; r < 4; r++) {
      const long row = m0 + wm + i * 16 + lq4 + r;
      #pragma unroll
      for (int j = 0; j < 4; j++) {
        const long col = n0 + wn + j * 16 + lr;
        float v = acc[i][j][r];
        if (ADD_RES) v += Res[row * (long)ldc + col];
        if (OUT_BF16) ((__bf16*)Cv)[row * (long)ldc + col] = (__bf16)v;
        else          ((float*)Cv)[row * (long)ldc + col] = v;
      }
    }
  }
}

// ---------------- gemm8p v5: 256x256 tile, 2 SYNC-PHASES per K-tile ------------------
// Same geometry/staging/swizzle/reads/MFMAs/epilogues as v3 (verified 983 TF); only the
// sync granularity changes: 2 phases/tile (4 barriers, 2 lgkm waits) instead of 4
// phases (8 barriers, 3-4 lgkm waits). Audited vmcnt accounting:
//   invariant at tile-T start: outstanding = {A1(T)} = 2 loads (newest).
//   P_a: read A0,B0,B1(T) (16x b128, landed per prev P_b vmcnt(2)+barrier);
//        stage A0',B0',B1' (+6 -> 8); bar; lgkm0; q(0,0)+q(0,1) (32 MFMA);
//        vmcnt(6) -> oldest 2 = A1(T) landed; bar.
//   P_b: read A1(T) (8x b128); stage A1' (+2 -> 8); bar; lgkm0; q(1,0)+q(1,1);
//        vmcnt(2) -> oldest 6 = A0'B0'B1' landed; bar.   [tail: vmcnt(0) at P_a / none]
// All stage-vs-read hazards stay barrier-separated (stages write nb only, reads cb).
template<bool ROPE, bool SILU>
__global__ __launch_bounds__(512, 2) void gemm8p(const __bf16* __restrict__ A, int lda,
                                                 const __bf16* __restrict__ B, int ldb,
                                                 void* Cv, int ldc, int K) {
  __shared__ __align__(16) __bf16 As[2 * 16384];   // 2 x 32 KiB
  __shared__ __align__(16) __bf16 Bs[2 * 16384];   // 2 x 32 KiB
  const int tid  = threadIdx.x;
  const int lane = tid & 63;
  const int w    = tid >> 6;
  const int wm2  = w >> 2;        // 0..1
  const int wn4  = w & 3;         // 0..3
  const int lr   = lane & 15;
  const int lq   = lane >> 4;
  const int m0   = blockIdx.y * 256;
  const int n0   = ROPE ? blockIdx.x * 256 : 0;
  const int n0c  = SILU ? blockIdx.x * 128 : 0;

  const long r0 = tid >> 3;
  const int  e  = (((tid & 7) ^ ((int)r0 & 7)) * 8);
  const __bf16* Ap0 = A + (long)(m0 + r0) * lda + e;
  long br0, br1, bhs;
  if (ROPE) {
    br0 = n0 + 64 * (((int)r0 >> 5) & 3) + ((int)r0 & 31);
    br1 = n0 + 64 * ((((int)r0 + 64) >> 5) & 3) + ((int)r0 & 31);
    bhs = 32 * (long)ldb;
  } else {
    br0 = n0c + r0;
    br1 = n0c + r0 + 64;
    bhs = (long)INTER_ * ldb;
  }
  const __bf16* Bp0 = B + br0 * ldb + e;
  const __bf16* Bp1 = B + br1 * ldb + e;
  char* sA = (char*)As;
  char* sB = (char*)Bs;
  const int tid16 = tid * 16;

#define STAGE_A(h_, nb_, kk_) do {                                                     \
    async16(Ap0 + (long)((h_) * 128) * lda + (kk_),      sA + (nb_)*32768 + (h_)*16384 + tid16);        \
    async16(Ap0 + (long)((h_) * 128 + 64) * lda + (kk_), sA + (nb_)*32768 + (h_)*16384 + 8192 + tid16); \
  } while (0)
#define STAGE_B(h_, nb_, kk_) do {                                                     \
    async16(Bp0 + (h_) * bhs + (kk_), sB + (nb_)*32768 + (h_)*16384 + tid16);          \
    async16(Bp1 + (h_) * bhs + (kk_), sB + (nb_)*32768 + (h_)*16384 + 8192 + tid16);   \
  } while (0)

  const int ch0 = ((lq ^ (lr & 7)) * 16);
  const int ch1 = (((4 + lq) ^ (lr & 7)) * 16);
  const int abase = (wm2 * 64 + lr) * 128;
  const int bbase = (wn4 * 32 + lr) * 128;

  f32x4 acc[8][4] = {};
  bf16x8 af[4][2], bfr[4][2];
  const int NT = K >> 6;

#define LOAD_A(mh_) do {                                                               \
    _Pragma("unroll")                                                                  \
    for (int i = 0; i < 4; i++) {                                                      \
      af[i][0] = *(const bf16x8*)(Ab + abase + (mh_)*16384 + i*2048 + ch0);            \
      af[i][1] = *(const bf16x8*)(Ab + abase + (mh_)*16384 + i*2048 + ch1);            \
    } } while (0)
#define LOAD_B(nh_) do {                                                               \
    _Pragma("unroll")                                                                  \
    for (int j = 0; j < 2; j++) {                                                      \
      bfr[(nh_)*2 + j][0] = *(const bf16x8*)(Bb + bbase + (nh_)*16384 + j*2048 + ch0); \
      bfr[(nh_)*2 + j][1] = *(const bf16x8*)(Bb + bbase + (nh_)*16384 + j*2048 + ch1); \
    } } while (0)
#define MFMA_Q(mh_, nh_) do {                                                          \
    __builtin_amdgcn_s_setprio(1);                                                     \
    _Pragma("unroll")                                                                  \
    for (int ks = 0; ks < 2; ks++)                                                     \
      _Pragma("unroll")                                                                \
      for (int i = 0; i < 4; i++)                                                      \
        _Pragma("unroll")                                                              \
        for (int j = 0; j < 2; j++)                                                    \
          acc[(mh_)*4 + i][(nh_)*2 + j] = __builtin_amdgcn_mfma_f32_16x16x32_bf16(     \
              af[i][ks], bfr[(nh_)*2 + j][ks], acc[(mh_)*4 + i][(nh_)*2 + j], 0, 0, 0);\
    __builtin_amdgcn_s_setprio(0);                                                     \
  } while (0)
#define SBAR() do { __builtin_amdgcn_sched_barrier(0);                                 \
    __builtin_amdgcn_s_barrier(); __builtin_amdgcn_sched_barrier(0); } while (0)
#define LGKM0() do { asm volatile("s_waitcnt lgkmcnt(0)" ::: "memory");                \
    __builtin_amdgcn_sched_barrier(0); } while (0)

  // prologue: stage tile 0 as A0,B0,B1,A1 (8 loads); wait so A0,B0,B1 landed,
  // A1 (newest 2) stays in flight.
  STAGE_A(0, 0, 0); STAGE_B(0, 0, 0); STAGE_B(1, 0, 0); STAGE_A(1, 0, 0);
  asm volatile("s_waitcnt vmcnt(2)" ::: "memory");
  SBAR();

  for (int T = 0; T < NT; ++T) {
    const int cb = T & 1, nb = cb ^ 1;
    const int kk = (T + 1) << 6;
    const bool st = (T + 1 < NT);
    const char* Ab = (const char*)As + cb * 32768;
    const char* Bb = (const char*)Bs + cb * 32768;
    // ---- P_a: read A0,B0,B1; stage A0',B0',B1'; MFMA q(0,0)+q(0,1) ----
    LOAD_A(0); LOAD_B(0); LOAD_B(1);
    if (st) { STAGE_A(0, nb, kk); STAGE_B(0, nb, kk); STAGE_B(1, nb, kk); }
    SBAR(); LGKM0();
    MFMA_Q(0, 0);
    MFMA_Q(0, 1);
    if (st) asm volatile("s_waitcnt vmcnt(6)" ::: "memory");   // A1(T) landed
    else    asm volatile("s_waitcnt vmcnt(0)" ::: "memory");
    SBAR();
    // ---- P_b: read A1; stage A1'; MFMA q(1,0)+q(1,1) ----
    LOAD_A(1);
    if (st) STAGE_A(1, nb, kk);
    SBAR(); LGKM0();
    MFMA_Q(1, 0);
    MFMA_Q(1, 1);
    if (st) asm volatile("s_waitcnt vmcnt(2)" ::: "memory");   // A0',B0',B1' landed
    SBAR();
  }
#undef STAGE_A
#undef STAGE_B
#undef LOAD_A
#undef LOAD_B
#undef MFMA_Q
#undef SBAR
#undef LGKM0

  const int lq4 = lq * 4;
  if (ROPE) {
    if (n0 < 4096) {
      const float invf0 = exp2f((float)(lr)      * -0.41524101186092029f);
      const float invf1 = exp2f((float)(16 + lr) * -0.41524101186092029f);
      #pragma unroll
      for (int mi = 0; mi < 8; mi++) {
        #pragma unroll
        for (int r = 0; r < 4; r++) {
          const long row = m0 + (mi >> 2) * 128 + wm2 * 64 + (mi & 3) * 16 + lq4 + r;
          const float s = (float)(int)(row & (SEQLEN - 1));
          __bf16* crow = (__bf16*)Cv + row * (long)ldc + n0 + wn4 * 64 + lr;
          #pragma unroll
          for (int nj = 0; nj < 2; nj++) {
            float x1 = acc[mi][nj][r], x2 = acc[mi][nj + 2][r];
            float ang = s * (nj ? invf1 : invf0);
            float sn, cs;
            __sincosf(ang, &sn, &cs);
            crow[nj * 16]      = (__bf16)(x1 * cs - x2 * sn);
            crow[nj * 16 + 32] = (__bf16)(x2 * cs + x1 * sn);
          }
        }
      }
    } else {
      #pragma unroll
      for (int mi = 0; mi < 8; mi++) {
        #pragma unroll
        for (int r = 0; r < 4; r++) {
          const long row = m0 + (mi >> 2) * 128 + wm2 * 64 + (mi & 3) * 16 + lq4 + r;
          __bf16* crow = (__bf16*)Cv + row * (long)ldc + n0 + wn4 * 64 + lr;
          #pragma unroll
          for (int njf = 0; njf < 4; njf++)
            crow[(njf >> 1) * 32 + (njf & 1) * 16] = (__bf16)acc[mi][njf][r];
        }
      }
    }
  } else {  // SILU
    #pragma unroll
    for (int mi = 0; mi < 8; mi++) {
      #pragma unroll
      for (int r = 0; r < 4; r++) {
        const long row = m0 + (mi >> 2) * 128 + wm2 * 64 + (mi & 3) * 16 + lq4 + r;
        #pragma unroll
        for (int nj = 0; nj < 2; nj++) {
          const long col = n0c + wn4 * 32 + nj * 16 + lr;
          float g = acc[mi][nj][r];
          float v = acc[mi][nj + 2][r];
          float sg = g / (1.0f + __expf(-g));
          ((__bf16*)Cv)[row * (long)ldc + col] = (__bf16)(sg * v);
        }
      }
    }
  }
}

// ---------------- block-local flash attention v3 (round-3, verified) ----------------
__global__ __launch_bounds__(256) void attn_kernel(const __bf16* __restrict__ qkv,
                                                   __bf16* __restrict__ ctx) {
  const int qt   = blockIdx.x;
  const int head = blockIdx.y;
  const int b    = blockIdx.z;
  const int w    = threadIdx.x >> 6;
  const int lane = threadIdx.x & 63;
  const int lr = lane & 15;
  const int lq = lane >> 4;
  const int q0   = qt * 64;
  const int blk0 = q0 & ~511;
  const int nkv  = q0 + 64 - blk0;    // multiple of 64
  const int NT   = nkv >> 5;          // even
  const long tok0 = (long)b * SEQLEN;

  const int qrow = q0 + w * 16 + lr;
  const long qoff = (tok0 + qrow) * QKV_W + head * 64 + lq * 8;
  bf16x8 qf0 = *(const bf16x8*)(qkv + qoff);
  bf16x8 qf1 = *(const bf16x8*)(qkv + qoff + 32);

  __shared__ __align__(16) char VTb[8192];   // V^T: d-rows of 128B, 2 kv-halves of 4 chunks
  __shared__ __align__(16) char Pbb[8192];   // per-wave P: q-rows of 128B, 2 halves

  const __bf16* kp = qkv + (tok0 + blk0 + lr) * QKV_W + HID + head * 64 + lq * 8;
  const int skv = threadIdx.x & 31;
  const int sd0 = (threadIdx.x >> 5) * 8;
  const __bf16* vp = qkv + (tok0 + blk0 + skv) * QKV_W + 2 * HID + head * 64 + sd0;

  bf16x8 ka[2][2], kb[2][2];

#define LOADK(KN, tk) do { \
    KN[0][0] = *(const bf16x8*)(kp + (long)(tk) * QKV_W); \
    KN[0][1] = *(const bf16x8*)(kp + (long)(tk) * QKV_W + 32); \
    KN[1][0] = *(const bf16x8*)(kp + (long)((tk) + 16) * QKV_W); \
    KN[1][1] = *(const bf16x8*)(kp + (long)((tk) + 16) * QKV_W + 32); \
  } while (0)

#define WRITEV(vr_, hb_) do { \
    const int c_ = (hb_) * 4 + (skv >> 3); \
    char* vb_ = VTb + sd0 * 128 + ((skv & 7) * 2); \
    _Pragma("unroll") \
    for (int i_ = 0; i_ < 8; i_++) \
      *(__bf16*)(vb_ + i_ * 128 + ((c_ ^ i_) * 16)) = vr_[i_]; \
  } while (0)

  LOADK(ka, 0);
  {
    bf16x8 vr0 = *(const bf16x8*)(vp);
    WRITEV(vr0, 0);
  }
  __syncthreads();

  float m[4], l[4];
  f32x4 oacc[4] = {};
  #pragma unroll
  for (int r = 0; r < 4; r++) { m[r] = -1e30f; l[r] = 0.0f; }
  const int myrow = q0 + w * 16 + lq * 4;

#define ITER(t_, hb_, KC, KN) { \
    const int tkn_ = ((t_) + 1) * 32; \
    const bool more_ = ((t_) + 1 < NT); \
    bf16x8 vr_ = {}; \
    if (more_) { LOADK(KN, tkn_); vr_ = *(const bf16x8*)(vp + (long)tkn_ * QKV_W); } \
    f32x4 s0 = {0.f, 0.f, 0.f, 0.f}, s1 = {0.f, 0.f, 0.f, 0.f}; \
    s0 = __builtin_amdgcn_mfma_f32_16x16x32_bf16(qf0, KC[0][0], s0, 0, 0, 0); \
    s0 = __builtin_amdgcn_mfma_f32_16x16x32_bf16(qf1, KC[0][1], s0, 0, 0, 0); \
    s1 = __builtin_amdgcn_mfma_f32_16x16x32_bf16(qf0, KC[1][0], s1, 0, 0, 0); \
    s1 = __builtin_amdgcn_mfma_f32_16x16x32_bf16(qf1, KC[1][1], s1, 0, 0, 0); \
    const int kpos0_ = blk0 + (t_) * 32 + lr; \
    float p0[4], p1[4], alpha[4]; \
    _Pragma("unroll") \
    for (int r = 0; r < 4; r++) { \
      float v0 = s0[r] * 0.125f, v1 = s1[r] * 0.125f; \
      v0 = (kpos0_      <= myrow + r) ? v0 : -1e30f; \
      v1 = (kpos0_ + 16 <= myrow + r) ? v1 : -1e30f; \
      float mx = fmaxf(v0, v1); \
      mx = fmaxf(mx, __shfl_xor(mx, 1)); \
      mx = fmaxf(mx, __shfl_xor(mx, 2)); \
      mx = fmaxf(mx, __shfl_xor(mx, 4)); \
      mx = fmaxf(mx, __shfl_xor(mx, 8)); \
      float mn = fmaxf(m[r], mx); \
      alpha[r] = __expf(m[r] - mn); \
      m[r] = mn; \
      p0[r] = __expf(v0 - mn); \
      p1[r] = __expf(v1 - mn); \
      float rs = p0[r] + p1[r]; \
      rs += __shfl_xor(rs, 1); rs += __shfl_xor(rs, 2); \
      rs += __shfl_xor(rs, 4); rs += __shfl_xor(rs, 8); \
      l[r] = l[r] * alpha[r] + rs; \
    } \
    _Pragma("unroll") \
    for (int dt = 0; dt < 4; dt++) \
      _Pragma("unroll") \
      for (int r = 0; r < 4; r++) oacc[dt][r] *= alpha[r]; \
    { \
      char* pw_ = Pbb + w * 2048 + (lq * 4) * 128 + ((lr & 7) * 2); \
      const int cl_ = (hb_) * 4 + (lr >> 3); \
      _Pragma("unroll") \
      for (int r = 0; r < 4; r++) { \
        const int q7_ = (lq * 4 + r) & 7; \
        *(__bf16*)(pw_ + r * 128 + (((cl_    ) ^ q7_) * 16)) = (__bf16)p0[r]; \
        *(__bf16*)(pw_ + r * 128 + (((cl_ + 2) ^ q7_) * 16)) = (__bf16)p1[r]; \
      } \
    } \
    asm volatile("s_waitcnt lgkmcnt(0)" ::: "memory"); \
    const int swz_ = (((hb_) * 4 + lq) ^ (lr & 7)) * 16; \
    bf16x8 pf_ = *(const bf16x8*)(Pbb + w * 2048 + lr * 128 + swz_); \
    _Pragma("unroll") \
    for (int dt = 0; dt < 4; dt++) { \
      bf16x8 vf_ = *(const bf16x8*)(VTb + dt * 2048 + lr * 128 + swz_); \
      oacc[dt] = __builtin_amdgcn_mfma_f32_16x16x32_bf16(pf_, vf_, oacc[dt], 0, 0, 0); \
    } \
    __syncthreads(); \
    if (more_) WRITEV(vr_, (hb_) ^ 1); \
    __syncthreads(); \
  }

  for (int t2 = 0; t2 < NT; t2 += 2) {
    ITER(t2, 0, ka, kb)
    ITER(t2 + 1, 1, kb, ka)
  }
#undef ITER
#undef LOADK
#undef WRITEV

  #pragma unroll
  for (int r = 0; r < 4; r++) {
    float inv = 1.0f / l[r];
    long obase = (tok0 + myrow + r) * HID + head * 64;
    #pragma unroll
    for (int dt = 0; dt < 4; dt++)
      ctx[obase + dt * 16 + lr] = (__bf16)(oacc[dt][r] * inv);
  }
}

extern "C" void kernel_launch(void* const* d_in, const int* in_sizes, int n_in,
                              void* d_out, int out_size, void* d_ws, size_t ws_size,
                              hipStream_t stream) {
  const float* x      = (const float*)d_in[0];
  const float* anw    = (const float*)d_in[1];
  const float* fnw    = (const float*)d_in[2];
  const float* w_qkv  = (const float*)d_in[3];
  const float* w_o    = (const float*)d_in[4];
  const float* w_up   = (const float*)d_in[5];
  const float* w_down = (const float*)d_in[6];
  float* out = (float*)d_out;

  char* wsb = (char*)d_ws;
  __bf16* ABUF = (__bf16*)wsb;                        // 16 MiB: h1 / ctx / h2
  __bf16* QKV  = (__bf16*)(wsb + (size_t)16777216);   // 50.3 MiB: qkv; later act (33.5 MiB)
  __bf16* WBUF = (__bf16*)(wsb + (size_t)83886080);   // <=33.5 MiB: bf16 weight scratch
  __bf16* ACT  = QKV;                                  // reuse after attention

  // attention half
  rmsnorm_kernel<<<TOKENS, 256, 0, stream>>>(x, anw, ABUF);
  cvt_kernel<<<(QKV_W * HID / 4 + 255) / 256, 256, 0, stream>>>(w_qkv, WBUF, QKV_W * HID / 4);
  // Q,K (rope fused) via 2-sync-phase gemm8p: grid 16x16 = 256 blocks = exactly 1 round
  gemm8p<true, false><<<dim3(4096 / 256, TOKENS / 256), 512, 0, stream>>>(
      ABUF, HID, WBUF, HID, (void*)QKV, QKV_W, HID);
  // V (plain) via old kernel: grid 16x32 = 512 blocks, full chip
  gemm_bt<true, false, false, false><<<dim3(HID / 128, TOKENS / 128), 256, 0, stream>>>(
      ABUF, HID, WBUF + (size_t)4096 * HID, HID, (void*)(QKV + 4096), QKV_W, nullptr, HID);
  attn_kernel<<<dim3(SEQLEN / 64, 32, 2), 256, 0, stream>>>(QKV, ABUF);
  cvt_kernel<<<(HID * HID / 4 + 255) / 256, 256, 0, stream>>>(w_o, WBUF, HID * HID / 4);
  gemm_bt<false, true, false, false><<<dim3(HID / 128, TOKENS / 128), 256, 0, stream>>>(
      ABUF, HID, WBUF, HID, (void*)out, HID, x, HID);   // out = x + ctx@w_o^T

  // ffn half
  rmsnorm_kernel<<<TOKENS, 256, 0, stream>>>(out, fnw, ABUF);
  cvt_kernel<<<(UP_W * HID / 4 + 255) / 256, 256, 0, stream>>>(w_up, WBUF, UP_W * HID / 4);
  // fused up+silu via 2-sync-phase gemm8p: grid 32x16 = 512 blocks = 2 exact rounds
  gemm8p<false, true><<<dim3(INTER_ / 128, TOKENS / 256), 512, 0, stream>>>(
      ABUF, HID, WBUF, HID, (void*)ACT, INTER_, HID);
  cvt_kernel<<<(HID * INTER_ / 4 + 255) / 256, 256, 0, stream>>>(w_down, WBUF, HID * INTER_ / 4);
  gemm_bt<false, true, false, false><<<dim3(HID / 128, TOKENS / 128), 256, 0, stream>>>(
      ACT, INTER_, WBUF, INTER_, (void*)out, HID, out, INTER_); // out += act@w_down^T
}

// Round 11
// 554.565 us; speedup vs baseline: 2.5993x; 1.0100x over previous
//
#include <hip/hip_runtime.h>
#include <cstdint>
#include <cstddef>

typedef __bf16 bf16x8 __attribute__((ext_vector_type(8)));
typedef __bf16 bf16x4 __attribute__((ext_vector_type(4)));
typedef float  f32x4  __attribute__((ext_vector_type(4)));

#define TOKENS  4096
#define SEQLEN  2048
#define HID     2048
#define QKV_W   6144
#define UP_W    8192
#define INTER_  4096

__device__ __forceinline__ void async16(const void* g, void* l) {
  __builtin_amdgcn_global_load_lds(
      (__attribute__((address_space(1))) void*)(g),
      (__attribute__((address_space(3))) void*)(l), 16, 0, 0);
}

// ---------------- fp32 -> bf16 weight convert ----------------
__global__ __launch_bounds__(256) void cvt_kernel(const float* __restrict__ src,
                                                  __bf16* __restrict__ dst, int n4) {
  int i = blockIdx.x * 256 + threadIdx.x;
  if (i >= n4) return;
  float4 f = ((const float4*)src)[i];
  bf16x4 o;
  o[0] = (__bf16)f.x; o[1] = (__bf16)f.y; o[2] = (__bf16)f.z; o[3] = (__bf16)f.w;
  ((bf16x4*)dst)[i] = o;
}

// ---------------- rmsnorm: fp32 in -> bf16 out ----------------
__global__ __launch_bounds__(256) void rmsnorm_kernel(const float* __restrict__ x,
                                                      const float* __restrict__ wgt,
                                                      __bf16* __restrict__ out) {
  const int tok = blockIdx.x;
  const int t = threadIdx.x;
  const float4* xr = (const float4*)(x + (long)tok * HID);
  float4 a = xr[t], b = xr[t + 256];
  float ss = a.x*a.x + a.y*a.y + a.z*a.z + a.w*a.w
           + b.x*b.x + b.y*b.y + b.z*b.z + b.w*b.w;
  #pragma unroll
  for (int off = 32; off; off >>= 1) ss += __shfl_xor(ss, off);
  __shared__ float red[4];
  if ((t & 63) == 0) red[t >> 6] = ss;
  __syncthreads();
  float tot = red[0] + red[1] + red[2] + red[3];
  float r = rsqrtf(tot * (1.0f / HID) + 1e-5f);
  const float4* wr = (const float4*)wgt;
  float4 wa = wr[t], wb = wr[t + 256];
  bf16x4 o0, o1;
  o0[0] = (__bf16)(a.x * r * wa.x); o0[1] = (__bf16)(a.y * r * wa.y);
  o0[2] = (__bf16)(a.z * r * wa.z); o0[3] = (__bf16)(a.w * r * wa.w);
  o1[0] = (__bf16)(b.x * r * wb.x); o1[1] = (__bf16)(b.y * r * wb.y);
  o1[2] = (__bf16)(b.z * r * wb.z); o1[3] = (__bf16)(b.w * r * wb.w);
  bf16x4* orow = (bf16x4*)(out + (long)tok * HID);
  orow[t] = o0; orow[t + 256] = o1;
}

// ---------------- OLD BK=64 bf16 GEMM (round-0, verified) -- O, Down, V-proj ----
template<bool OUT_BF16, bool ADD_RES, bool ROPE, bool SILU>
__global__ __launch_bounds__(256) void gemm_bt(const __bf16* __restrict__ A, int lda,
                                               const __bf16* __restrict__ B, int ldb,
                                               void* Cv, int ldc,
                                               const float* __restrict__ Res, int K) {
  __shared__ __align__(16) __bf16 As[128 * 64];
  __shared__ __align__(16) __bf16 Bs[128 * 64];
  const int t = threadIdx.x;
  const int lane = t & 63;
  const int w = t >> 6;
  const int wm = (w >> 1) * 64, wn = (w & 1) * 64;
  const int m0 = blockIdx.y * 128;
  const int n0 = SILU ? blockIdx.x * 64 : blockIdx.x * 128;
  const int sr = t >> 3;
  const int sc = (((t & 7) ^ (sr & 7)) * 8);
  const __bf16* Ag = A + (long)(m0 + sr) * lda + sc;
  const __bf16* Bg = B + (long)(n0 + sr) * ldb + sc;
  char* lA = (char*)As + t * 16;
  char* lB = (char*)Bs + t * 16;
  const int lr = lane & 15;
  const int lq = lane >> 4;
  f32x4 acc[4][4] = {};
  for (int k0 = 0; k0 < K; k0 += 64) {
    __syncthreads();
    #pragma unroll
    for (int c = 0; c < 4; c++)
      async16(Ag + (long)(c * 32) * lda + k0, lA + c * 4096);
    #pragma unroll
    for (int c = 0; c < 4; c++) {
      const long rowoff = SILU ? (long)((c & 1) * INTER_ + (c >> 1) * 32) * ldb
                               : (long)(c * 32) * ldb;
      async16(Bg + rowoff + k0, lB + c * 4096);
    }
    __syncthreads();
    #pragma unroll
    for (int ks = 0; ks < 2; ks++) {
      const int pos = (((ks * 4 + lq) ^ (lr & 7)) * 8);
      bf16x8 af[4], bfr[4];
      #pragma unroll
      for (int i = 0; i < 4; i++)
        af[i]  = *(const bf16x8*)(As + (wm + i * 16 + lr) * 64 + pos);
      #pragma unroll
      for (int j = 0; j < 4; j++)
        bfr[j] = *(const bf16x8*)(Bs + (wn + j * 16 + lr) * 64 + pos);
      #pragma unroll
      for (int i = 0; i < 4; i++)
        #pragma unroll
        for (int j = 0; j < 4; j++)
          acc[i][j] = __builtin_amdgcn_mfma_f32_16x16x32_bf16(af[i], bfr[j], acc[i][j], 0, 0, 0);
    }
  }
  const int lq4 = lq * 4;
  #pragma unroll
  for (int i = 0; i < 4; i++) {
    #pragma unroll
    for (int r = 0; r < 4; r++) {
      const long row = m0 + wm + i * 16 + lq4 + r;
      #pragma unroll
      for (int j = 0; j < 4; j++) {
        const long col = n0 + wn + j * 16 + lr;
        float v = acc[i][j][r];
        if (ADD_RES) v += Res[row * (long)ldc + col];
        if (OUT_BF16) ((__bf16*)Cv)[row * (long)ldc + col] = (__bf16)v;
        else          ((float*)Cv)[row * (long)ldc + col] = v;
      }
    }
  }
}

// ---------------- 8-phase 256x256 pipelined GEMM v3 (verified 983 TF) -- QK, Up -------
template<bool ROPE, bool SILU>
__global__ __launch_bounds__(512, 2) void gemm8p(const __bf16* __restrict__ A, int lda,
                                                 const __bf16* __restrict__ B, int ldb,
                                                 void* Cv, int ldc, int K) {
  __shared__ __align__(16) __bf16 As[2 * 16384];   // 2 x 32 KiB
  __shared__ __align__(16) __bf16 Bs[2 * 16384];   // 2 x 32 KiB
  const int tid  = threadIdx.x;
  const int lane = tid & 63;
  const int w    = tid >> 6;
  const int wm2  = w >> 2;        // 0..1
  const int wn4  = w & 3;         // 0..3
  const int lr   = lane & 15;
  const int lq   = lane >> 4;
  const int m0   = blockIdx.y * 256;
  const int n0   = ROPE ? blockIdx.x * 256 : 0;
  const int n0c  = SILU ? blockIdx.x * 128 : 0;

  const long r0 = tid >> 3;
  const int  e  = (((tid & 7) ^ ((int)r0 & 7)) * 8);
  const __bf16* Ap0 = A + (long)(m0 + r0) * lda + e;
  long br0, br1, bhs;
  if (ROPE) {
    br0 = n0 + 64 * (((int)r0 >> 5) & 3) + ((int)r0 & 31);
    br1 = n0 + 64 * ((((int)r0 + 64) >> 5) & 3) + ((int)r0 & 31);
    bhs = 32 * (long)ldb;
  } else {
    br0 = n0c + r0;
    br1 = n0c + r0 + 64;
    bhs = (long)INTER_ * ldb;
  }
  const __bf16* Bp0 = B + br0 * ldb + e;
  const __bf16* Bp1 = B + br1 * ldb + e;
  char* sA = (char*)As;
  char* sB = (char*)Bs;
  const int tid16 = tid * 16;

#define STAGE_A(h_, nb_, kk_) do {                                                     \
    async16(Ap0 + (long)((h_) * 128) * lda + (kk_),      sA + (nb_)*32768 + (h_)*16384 + tid16);        \
    async16(Ap0 + (long)((h_) * 128 + 64) * lda + (kk_), sA + (nb_)*32768 + (h_)*16384 + 8192 + tid16); \
  } while (0)
#define STAGE_B(h_, nb_, kk_) do {                                                     \
    async16(Bp0 + (h_) * bhs + (kk_), sB + (nb_)*32768 + (h_)*16384 + tid16);          \
    async16(Bp1 + (h_) * bhs + (kk_), sB + (nb_)*32768 + (h_)*16384 + 8192 + tid16);   \
  } while (0)

  const int ch0 = ((lq ^ (lr & 7)) * 16);
  const int ch1 = (((4 + lq) ^ (lr & 7)) * 16);
  const int abase = (wm2 * 64 + lr) * 128;
  const int bbase = (wn4 * 32 + lr) * 128;

  f32x4 acc[8][4] = {};
  bf16x8 af[4][2], bfr[4][2];
  const int NT = K >> 6;

#define LOAD_A(mh_) do {                                                               \
    _Pragma("unroll")                                                                  \
    for (int i = 0; i < 4; i++) {                                                      \
      af[i][0] = *(const bf16x8*)(Ab + abase + (mh_)*16384 + i*2048 + ch0);            \
      af[i][1] = *(const bf16x8*)(Ab + abase + (mh_)*16384 + i*2048 + ch1);            \
    } } while (0)
#define LOAD_B(nh_) do {                                                               \
    _Pragma("unroll")                                                                  \
    for (int j = 0; j < 2; j++) {                                                      \
      bfr[(nh_)*2 + j][0] = *(const bf16x8*)(Bb + bbase + (nh_)*16384 + j*2048 + ch0); \
      bfr[(nh_)*2 + j][1] = *(const bf16x8*)(Bb + bbase + (nh_)*16384 + j*2048 + ch1); \
    } } while (0)
#define MFMA_Q(mh_, nh_) do {                                                          \
    __builtin_amdgcn_s_setprio(1);                                                     \
    _Pragma("unroll")                                                                  \
    for (int ks = 0; ks < 2; ks++)                                                     \
      _Pragma("unroll")                                                                \
      for (int i = 0; i < 4; i++)                                                      \
        _Pragma("unroll")                                                              \
        for (int j = 0; j < 2; j++)                                                    \
          acc[(mh_)*4 + i][(nh_)*2 + j] = __builtin_amdgcn_mfma_f32_16x16x32_bf16(     \
              af[i][ks], bfr[(nh_)*2 + j][ks], acc[(mh_)*4 + i][(nh_)*2 + j], 0, 0, 0);\
    __builtin_amdgcn_s_setprio(0);                                                     \
  } while (0)
#define SBAR() do { __builtin_amdgcn_sched_barrier(0);                                 \
    __builtin_amdgcn_s_barrier(); __builtin_amdgcn_sched_barrier(0); } while (0)
#define LGKM0() do { asm volatile("s_waitcnt lgkmcnt(0)" ::: "memory");                \
    __builtin_amdgcn_sched_barrier(0); } while (0)

  STAGE_A(0, 0, 0); STAGE_B(0, 0, 0); STAGE_B(1, 0, 0); STAGE_A(1, 0, 0);
  asm volatile("s_waitcnt vmcnt(4)" ::: "memory");
  SBAR();

  for (int T = 0; T < NT; ++T) {
    const int cb = T & 1, nb = cb ^ 1;
    const int kk = (T + 1) << 6;
    const bool st = (T + 1 < NT);
    const char* Ab = (const char*)As + cb * 32768;
    const char* Bb = (const char*)Bs + cb * 32768;
    LOAD_A(0); LOAD_B(0);
    if (st) { STAGE_A(0, nb, kk); STAGE_B(0, nb, kk); }
    SBAR(); LGKM0();
    MFMA_Q(0, 0);
    if (st) asm volatile("s_waitcnt vmcnt(6)" ::: "memory");
    else    asm volatile("s_waitcnt vmcnt(2)" ::: "memory");
    SBAR();
    LOAD_B(1);
    if (st) STAGE_B(1, nb, kk);
    SBAR(); LGKM0();
    MFMA_Q(0, 1);
    if (st) asm volatile("s_waitcnt vmcnt(6)" ::: "memory");
    else    asm volatile("s_waitcnt vmcnt(0)" ::: "memory");
    SBAR();
    LOAD_A(1);
    if (st) STAGE_A(1, nb, kk);
    SBAR(); LGKM0();
    MFMA_Q(1, 0);
    SBAR();
    MFMA_Q(1, 1);
    if (st) asm volatile("s_waitcnt vmcnt(4)" ::: "memory");
    SBAR();
  }
#undef STAGE_A
#undef STAGE_B
#undef LOAD_A
#undef LOAD_B
#undef MFMA_Q
#undef SBAR
#undef LGKM0

  const int lq4 = lq * 4;
  if (ROPE) {
    if (n0 < 4096) {
      const float invf0 = exp2f((float)(lr)      * -0.41524101186092029f);
      const float invf1 = exp2f((float)(16 + lr) * -0.41524101186092029f);
      #pragma unroll
      for (int mi = 0; mi < 8; mi++) {
        #pragma unroll
        for (int r = 0; r < 4; r++) {
          const long row = m0 + (mi >> 2) * 128 + wm2 * 64 + (mi & 3) * 16 + lq4 + r;
          const float s = (float)(int)(row & (SEQLEN - 1));
          __bf16* crow = (__bf16*)Cv + row * (long)ldc + n0 + wn4 * 64 + lr;
          #pragma unroll
          for (int nj = 0; nj < 2; nj++) {
            float x1 = acc[mi][nj][r], x2 = acc[mi][nj + 2][r];
            float ang = s * (nj ? invf1 : invf0);
            float sn, cs;
            __sincosf(ang, &sn, &cs);
            crow[nj * 16]      = (__bf16)(x1 * cs - x2 * sn);
            crow[nj * 16 + 32] = (__bf16)(x2 * cs + x1 * sn);
          }
        }
      }
    } else {
      #pragma unroll
      for (int mi = 0; mi < 8; mi++) {
        #pragma unroll
        for (int r = 0; r < 4; r++) {
          const long row = m0 + (mi >> 2) * 128 + wm2 * 64 + (mi & 3) * 16 + lq4 + r;
          __bf16* crow = (__bf16*)Cv + row * (long)ldc + n0 + wn4 * 64 + lr;
          #pragma unroll
          for (int njf = 0; njf < 4; njf++)
            crow[(njf >> 1) * 32 + (njf & 1) * 16] = (__bf16)acc[mi][njf][r];
        }
      }
    }
  } else {  // SILU
    #pragma unroll
    for (int mi = 0; mi < 8; mi++) {
      #pragma unroll
      for (int r = 0; r < 4; r++) {
        const long row = m0 + (mi >> 2) * 128 + wm2 * 64 + (mi & 3) * 16 + lq4 + r;
        #pragma unroll
        for (int nj = 0; nj < 2; nj++) {
          const long col = n0c + wn4 * 32 + nj * 16 + lr;
          float g = acc[mi][nj][r];
          float v = acc[mi][nj + 2][r];
          float sg = g / (1.0f + __expf(-g));
          ((__bf16*)Cv)[row * (long)ldc + col] = (__bf16)(sg * v);
        }
      }
    }
  }
}

// ---------------- flash attention v4: kv-step 64, single barrier/iter ----------------
// v3 was ~121us, latency-bound (avg 9 serial iters x {2 barriers, 32 shuffles,
// exposed K-load}). v4 halves the serial iteration count (kv tile 32->64) and uses ONE
// __syncthreads per iter (write targets buf^1; its previous readers are separated by
// the prior iteration's trailing barrier -- buffer-parity argument). All layout/swizzle
// formulas generalize from v3 verbatim: P chunk = nt*2+(lr>>3) (was hb*4+(lr>>3));
// PV swz chunk = h*4+lq (was hb*4+lq). K loaded at iter top (no reg ping-pong) to keep
// VGPR <= ~110 -> 4 waves/SIMD. V for t+1 loaded at iter top, written after PV (T14).
__global__ __launch_bounds__(256) void attn_kernel(const __bf16* __restrict__ qkv,
                                                   __bf16* __restrict__ ctx) {
  const int qt   = blockIdx.x;
  const int head = blockIdx.y;
  const int b    = blockIdx.z;
  const int w    = threadIdx.x >> 6;
  const int lane = threadIdx.x & 63;
  const int lr = lane & 15;
  const int lq = lane >> 4;
  const int q0   = qt * 64;
  const int blk0 = q0 & ~511;
  const int nkv  = q0 + 64 - blk0;    // multiple of 64
  const int NT   = nkv >> 6;          // 1..8
  const long tok0 = (long)b * SEQLEN;

  const int qrow = q0 + w * 16 + lr;
  const long qoff = (tok0 + qrow) * QKV_W + head * 64 + lq * 8;
  bf16x8 qf0 = *(const bf16x8*)(qkv + qoff);
  bf16x8 qf1 = *(const bf16x8*)(qkv + qoff + 32);

  __shared__ __align__(16) char VTb[2][8192];  // [buf][64 d][128B = 64 kv], XOR-swizzled
  __shared__ __align__(16) char Pbb[8192];     // [wave][16 q][128B = 64 kv], XOR-swizzled

  // V staging: 256 thr = 64 kv x 4 d-groups; each thread: kv=skv, d in {sd0..sd0+7, sd0+32..+39}
  const int skv = threadIdx.x & 63;
  const int sd0 = (threadIdx.x >> 6) * 8;      // 0,8,16,24
  const __bf16* vp = qkv + (tok0 + blk0 + skv) * QKV_W + 2 * HID + head * 64 + sd0;
  const __bf16* kp = qkv + (tok0 + blk0 + lr) * QKV_W + HID + head * 64 + lq * 8;

  // element (d, kv=skv): byte d*128 + ((skv>>3) ^ (d&7))*16 + (skv&7)*2; d&7 == i for both halves
#define WRITEV(va_, vb_, bf_) do { \
    const int c_ = skv >> 3; \
    char* p_ = VTb[bf_] + sd0 * 128 + ((skv & 7) * 2); \
    _Pragma("unroll") \
    for (int i_ = 0; i_ < 8; i_++) { \
      *(__bf16*)(p_ + i_ * 128 + ((c_ ^ i_) * 16))        = va_[i_]; \
      *(__bf16*)(p_ + (32 + i_) * 128 + ((c_ ^ i_) * 16)) = vb_[i_]; \
    } } while (0)

  // prologue: V tile 0 -> buf 0
  {
    bf16x8 va0 = *(const bf16x8*)(vp);
    bf16x8 vb0 = *(const bf16x8*)(vp + 32);
    WRITEV(va0, vb0, 0);
  }
  __syncthreads();

  float m[4], l[4];
  f32x4 oacc[4] = {};
  #pragma unroll
  for (int r = 0; r < 4; r++) { m[r] = -1e30f; l[r] = 0.0f; }
  const int myrow = q0 + w * 16 + lq * 4;

  for (int t = 0; t < NT; ++t) {
    const int bf = t & 1;
    const bool more = (t + 1 < NT);
    // V(t+1) issue-early (T14)
    bf16x8 va = {}, vb = {};
    if (more) {
      const __bf16* vq = vp + (long)((t + 1) * 64) * QKV_W;
      va = *(const bf16x8*)(vq);
      vb = *(const bf16x8*)(vq + 32);
    }
    // K for this tile: 4 slabs of 16 kv
    const __bf16* kpt = kp + (long)(t * 64) * QKV_W;
    bf16x8 kf[4][2];
    #pragma unroll
    for (int nt = 0; nt < 4; nt++) {
      kf[nt][0] = *(const bf16x8*)(kpt + (long)(nt * 16) * QKV_W);
      kf[nt][1] = *(const bf16x8*)(kpt + (long)(nt * 16) * QKV_W + 32);
    }
    f32x4 s[4];
    #pragma unroll
    for (int nt = 0; nt < 4; nt++) {
      f32x4 z = {0.f, 0.f, 0.f, 0.f};
      z = __builtin_amdgcn_mfma_f32_16x16x32_bf16(qf0, kf[nt][0], z, 0, 0, 0);
      z = __builtin_amdgcn_mfma_f32_16x16x32_bf16(qf1, kf[nt][1], z, 0, 0, 0);
      s[nt] = z;
    }
    const int kb0 = blk0 + t * 64 + lr;
    float p[4][4], alpha[4];
    #pragma unroll
    for (int r = 0; r < 4; r++) {
      float v0 = (kb0      <= myrow + r) ? s[0][r] * 0.125f : -1e30f;
      float v1 = (kb0 + 16 <= myrow + r) ? s[1][r] * 0.125f : -1e30f;
      float v2 = (kb0 + 32 <= myrow + r) ? s[2][r] * 0.125f : -1e30f;
      float v3 = (kb0 + 48 <= myrow + r) ? s[3][r] * 0.125f : -1e30f;
      float mx = fmaxf(fmaxf(v0, v1), fmaxf(v2, v3));
      mx = fmaxf(mx, __shfl_xor(mx, 1));
      mx = fmaxf(mx, __shfl_xor(mx, 2));
      mx = fmaxf(mx, __shfl_xor(mx, 4));
      mx = fmaxf(mx, __shfl_xor(mx, 8));
      float mn = fmaxf(m[r], mx);
      alpha[r] = __expf(m[r] - mn);
      m[r] = mn;
      p[0][r] = __expf(v0 - mn);
      p[1][r] = __expf(v1 - mn);
      p[2][r] = __expf(v2 - mn);
      p[3][r] = __expf(v3 - mn);
      float rs = (p[0][r] + p[1][r]) + (p[2][r] + p[3][r]);
      rs += __shfl_xor(rs, 1);
      rs += __shfl_xor(rs, 2);
      rs += __shfl_xor(rs, 4);
      rs += __shfl_xor(rs, 8);
      l[r] = l[r] * alpha[r] + rs;
    }
    #pragma unroll
    for (int dt = 0; dt < 4; dt++)
      #pragma unroll
      for (int r = 0; r < 4; r++) oacc[dt][r] *= alpha[r];
    // P -> LDS (swizzled): kv = nt*16 + lr -> chunk = nt*2 + (lr>>3), elem lr&7
    {
      char* pw = Pbb + w * 2048 + (lq * 4) * 128 + ((lr & 7) * 2);
      const int cb_ = lr >> 3;
      #pragma unroll
      for (int r = 0; r < 4; r++) {
        const int q7 = (lq * 4 + r) & 7;
        #pragma unroll
        for (int nt = 0; nt < 4; nt++)
          *(__bf16*)(pw + r * 128 + (((nt * 2 + cb_) ^ q7) * 16)) = (__bf16)p[nt][r];
      }
    }
    asm volatile("s_waitcnt lgkmcnt(0)" ::: "memory");
    // PV: K=64 as two 32-k halves h
    #pragma unroll
    for (int h = 0; h < 2; h++) {
      const int swz = (((h * 4 + lq) ^ (lr & 7)) * 16);
      bf16x8 pf = *(const bf16x8*)(Pbb + w * 2048 + lr * 128 + swz);
      #pragma unroll
      for (int dt = 0; dt < 4; dt++) {
        bf16x8 vf = *(const bf16x8*)(VTb[bf] + (dt * 16 + lr) * 128 + swz);
        oacc[dt] = __builtin_amdgcn_mfma_f32_16x16x32_bf16(pf, vf, oacc[dt], 0, 0, 0);
      }
    }
    if (more) {
      WRITEV(va, vb, bf ^ 1);
      __syncthreads();
    }
  }
#undef WRITEV

  #pragma unroll
  for (int r = 0; r < 4; r++) {
    float inv = 1.0f / l[r];
    long obase = (tok0 + myrow + r) * HID + head * 64;
    #pragma unroll
    for (int dt = 0; dt < 4; dt++)
      ctx[obase + dt * 16 + lr] = (__bf16)(oacc[dt][r] * inv);
  }
}

extern "C" void kernel_launch(void* const* d_in, const int* in_sizes, int n_in,
                              void* d_out, int out_size, void* d_ws, size_t ws_size,
                              hipStream_t stream) {
  const float* x      = (const float*)d_in[0];
  const float* anw    = (const float*)d_in[1];
  const float* fnw    = (const float*)d_in[2];
  const float* w_qkv  = (const float*)d_in[3];
  const float* w_o    = (const float*)d_in[4];
  const float* w_up   = (const float*)d_in[5];
  const float* w_down = (const float*)d_in[6];
  float* out = (float*)d_out;

  char* wsb = (char*)d_ws;
  __bf16* ABUF = (__bf16*)wsb;                        // 16 MiB: h1 / ctx / h2
  __bf16* QKV  = (__bf16*)(wsb + (size_t)16777216);   // 50.3 MiB: qkv; later act (33.5 MiB)
  __bf16* WBUF = (__bf16*)(wsb + (size_t)83886080);   // <=33.5 MiB: bf16 weight scratch
  __bf16* ACT  = QKV;                                  // reuse after attention

  // attention half
  rmsnorm_kernel<<<TOKENS, 256, 0, stream>>>(x, anw, ABUF);
  cvt_kernel<<<(QKV_W * HID / 4 + 255) / 256, 256, 0, stream>>>(w_qkv, WBUF, QKV_W * HID / 4);
  // Q,K (rope fused) via gemm8p v3: grid 16x16 = 256 blocks = exactly 1 round
  gemm8p<true, false><<<dim3(4096 / 256, TOKENS / 256), 512, 0, stream>>>(
      ABUF, HID, WBUF, HID, (void*)QKV, QKV_W, HID);
  // V (plain) via old kernel: grid 16x32 = 512 blocks, full chip
  gemm_bt<true, false, false, false><<<dim3(HID / 128, TOKENS / 128), 256, 0, stream>>>(
      ABUF, HID, WBUF + (size_t)4096 * HID, HID, (void*)(QKV + 4096), QKV_W, nullptr, HID);
  attn_kernel<<<dim3(SEQLEN / 64, 32, 2), 256, 0, stream>>>(QKV, ABUF);
  cvt_kernel<<<(HID * HID / 4 + 255) / 256, 256, 0, stream>>>(w_o, WBUF, HID * HID / 4);
  gemm_bt<false, true, false, false><<<dim3(HID / 128, TOKENS / 128), 256, 0, stream>>>(
      ABUF, HID, WBUF, HID, (void*)out, HID, x, HID);   // out = x + ctx@w_o^T

  // ffn half
  rmsnorm_kernel<<<TOKENS, 256, 0, stream>>>(out, fnw, ABUF);
  cvt_kernel<<<(UP_W * HID / 4 + 255) / 256, 256, 0, stream>>>(w_up, WBUF, UP_W * HID / 4);
  // fused up+silu via gemm8p v3: grid 32x16 = 512 blocks = 2 exact rounds
  gemm8p<false, true><<<dim3(INTER_ / 128, TOKENS / 256), 512, 0, stream>>>(
      ABUF, HID, WBUF, HID, (void*)ACT, INTER_, HID);
  cvt_kernel<<<(HID * INTER_ / 4 + 255) / 256, 256, 0, stream>>>(w_down, WBUF, HID * INTER_ / 4);
  gemm_bt<false, true, false, false><<<dim3(HID / 128, TOKENS / 128), 256, 0, stream>>>(
      ACT, INTER_, WBUF, INTER_, (void*)out, HID, out, INTER_); // out += act@w_down^T
}